// Round 15
// baseline (2031.816 us; speedup 1.0000x reference)
//
#include <hip/hip_runtime.h>
#include <hip/hip_bf16.h>
#include <hip/hip_fp16.h>
#include <cstdint>
#include <cstddef>

#define NNODES 100000
#define NEDGES 1600000
#define EMBD 128
#define NLAYER 5
#define XDIM 178
#define EDIM 18
#define BNEPS 1e-5f

typedef __attribute__((ext_vector_type(8))) short short8;
typedef __attribute__((ext_vector_type(8))) unsigned short ushort8;
typedef __attribute__((ext_vector_type(4))) float f32x4;

static __device__ __forceinline__ float leakyf(float v){ return v > 0.f ? v : 0.1f*v; }
static __device__ __forceinline__ unsigned short f2b(float v){
  __hip_bfloat16 b = __float2bfloat16(v);
  return *reinterpret_cast<unsigned short*>(&b);
}
static __device__ __forceinline__ float b2f(unsigned short u){
  __hip_bfloat16 b = *reinterpret_cast<__hip_bfloat16*>(&u);
  return __bfloat162float(b);
}
static __device__ __forceinline__ unsigned short f2h(float v){
  __half h = __float2half(v);
  return *reinterpret_cast<unsigned short*>(&h);
}
static __device__ __forceinline__ float h2f(unsigned short u){
  __half h = *reinterpret_cast<__half*>(&u);
  return __half2float(h);
}

// ---------------- CSR build ----------------
__global__ __launch_bounds__(256) void k_hist(const int* __restrict__ dst, int* __restrict__ cnt){
  int e = blockIdx.x*256 + threadIdx.x;
  if (e < NEDGES) atomicAdd(&cnt[dst[e]], 1);
}

__global__ __launch_bounds__(256) void k_scan1(const int* __restrict__ cnt, int* __restrict__ rowptr,
                                               int* __restrict__ bsum){
  __shared__ int s[256];
  int t = threadIdx.x, i = blockIdx.x*256 + t;
  int v = (i < NNODES) ? cnt[i] : 0;
  s[t] = v; __syncthreads();
  for (int off=1; off<256; off<<=1){
    int x = (t>=off) ? s[t-off] : 0; __syncthreads();
    s[t] += x; __syncthreads();
  }
  if (i < NNODES) rowptr[i+1] = s[t];
  if (t == 255) bsum[blockIdx.x] = s[t];
}

__global__ __launch_bounds__(512) void k_scan2(const int* __restrict__ bsum, int* __restrict__ boff, int nb){
  __shared__ int s[512];
  int t = threadIdx.x;
  int v = (t < nb) ? bsum[t] : 0;
  s[t] = v; __syncthreads();
  for (int off=1; off<512; off<<=1){
    int x = (t>=off) ? s[t-off] : 0; __syncthreads();
    s[t] += x; __syncthreads();
  }
  if (t < nb) boff[t] = s[t] - v;
}

__global__ __launch_bounds__(256) void k_scan3(int* __restrict__ rowptr, const int* __restrict__ boff){
  int i = blockIdx.x*256 + threadIdx.x;
  if (i < NNODES) rowptr[i+1] += boff[i>>8];
  if (i == 0) rowptr[0] = 0;
}

__global__ __launch_bounds__(256) void k_curcopy(const int* __restrict__ rowptr, int* __restrict__ cursor){
  int i = blockIdx.x*256 + threadIdx.x;
  if (i < NNODES) cursor[i] = rowptr[i];
}

// pass A: position + inverse permutation only (4B scatter into L2-resident 6.4MB array)
__global__ __launch_bounds__(256) void k_fill_pos(const int* __restrict__ dst, int* __restrict__ cursor,
                                                  int* __restrict__ einv){
  int e = blockIdx.x*256 + threadIdx.x;
  if (e >= NEDGES) return;
  int pos = atomicAdd(&cursor[dst[e]], 1);
  einv[pos] = e;
}

// pass B: pos-coalesced; random READS of ea rows; coalesced writes of eap24+srcp
__global__ __launch_bounds__(256) void k_fill_ea(const int* __restrict__ einv, const int* __restrict__ src,
                                                 const float* __restrict__ ea,
                                                 int* __restrict__ srcp, unsigned short* __restrict__ eap24){
  int pos = blockIdx.x*256 + threadIdx.x;
  if (pos >= NEDGES) return;
  int e = einv[pos];
  srcp[pos] = src[e];
  const float* a = ea + (size_t)e*EDIM;
  float v[18];
  #pragma unroll
  for (int k=0;k<9;++k){
    float2 t = *(const float2*)(a + 2*k);
    v[2*k] = t.x; v[2*k+1] = t.y;
  }
  ushort8 r0, r1, r2;
  #pragma unroll
  for (int k=0;k<8;++k) r0[k] = f2b(v[k]);
  #pragma unroll
  for (int k=0;k<8;++k) r1[k] = f2b(v[8+k]);
  #pragma unroll
  for (int k=0;k<8;++k) r2[k] = 0;
  r2[0] = f2b(v[16]); r2[1] = f2b(v[17]);
  r2[2] = 0x3F80;   // bf16 1.0 at k=18 -> bias slot
  unsigned short* o = eap24 + (size_t)pos*24;
  *reinterpret_cast<ushort8*>(o)      = r0;
  *reinterpret_cast<ushort8*>(o + 8)  = r1;
  *reinterpret_cast<ushort8*>(o + 16) = r2;
}

// old-path fill (fallback)
__global__ __launch_bounds__(256) void k_fill(const int* __restrict__ src, const int* __restrict__ dst,
                                              const float* __restrict__ ea, int* __restrict__ cursor,
                                              int* __restrict__ perm, int* __restrict__ srcp,
                                              float* __restrict__ eap){
  int e = blockIdx.x*256 + threadIdx.x;
  if (e >= NEDGES) return;
  int pos = atomicAdd(&cursor[dst[e]], 1);
  perm[pos] = e;
  srcp[pos] = src[e];
  if (eap){
    const float* a = ea + (size_t)e*EDIM;
    float* o = eap + (size_t)pos*EDIM;
    #pragma unroll
    for (int k=0;k<EDIM;++k) o[k] = a[k];
  }
}

// self_e[l] = leaky(eb1[l]) @ ew2[l] + eb2[l]
__global__ __launch_bounds__(128) void k_selfe(const float* __restrict__ eb1, const float* __restrict__ ew2,
                                               const float* __restrict__ eb2, float* __restrict__ selfe){
  int l = blockIdx.x, c = threadIdx.x;
  const float* b1 = eb1 + l*EMBD;
  const float* w2 = ew2 + (size_t)l*EMBD*EMBD;
  float acc = eb2[l*EMBD + c];
  for (int j=0;j<EMBD;++j) acc += leakyf(b1[j]) * w2[j*EMBD + c];
  selfe[l*EMBD + c] = acc;
}

// Wc[l] = ew2[l] @ mw1[l]  ([128][256] fp32)
__global__ __launch_bounds__(256) void k_wc(const float* __restrict__ ew2, const float* __restrict__ mw1,
                                            float* __restrict__ wc){
  int idx = blockIdx.x*256 + threadIdx.x;       // 5*128*256
  int l = idx >> 15, rem = idx & 32767;
  int i = rem >> 8, n = rem & 255;
  const float* e = ew2 + (size_t)l*EMBD*EMBD + i*EMBD;
  const float* m = mw1 + (size_t)l*EMBD*2*EMBD + n;
  float acc = 0.f;
  #pragma unroll 4
  for (int j=0;j<EMBD;++j) acc += e[j]*m[(size_t)j*2*EMBD];
  wc[idx] = acc;
}

// pack B [Kpad x N] into hi/lo bf16 planes laid out [ks][n][kk]
__global__ __launch_bounds__(256) void k_pack(const float* __restrict__ s1, int rows1,
                                              const float* __restrict__ s2, int Kreal,
                                              int Kpad, int N, __hip_bfloat16* __restrict__ out){
  int idx = blockIdx.x*256 + threadIdx.x;
  if (idx >= Kpad*N) return;
  int k = idx / N, n = idx - k*N;
  float v = 0.f;
  if (k < rows1) v = s1[(size_t)k*N + n];
  else if (k < Kreal) v = s2[(size_t)(k-rows1)*N + n];
  unsigned short hi = f2b(v);
  unsigned short lo = f2b(v - b2f(hi));
  size_t o = (size_t)(k>>5)*N*32 + (size_t)n*32 + (k&31);
  unsigned short* po = (unsigned short*)out;
  po[o] = hi;
  po[(size_t)Kpad*N + o] = lo;
}

// ------------- tier-N combined edge dispatch: 2-node-interleaved gather + S1 MFMA, fp16 outputs -------------
__global__ __launch_bounds__(256) void k_edge4(
    const unsigned short* __restrict__ hh, const int* __restrict__ rowptr,
    const int* __restrict__ srcp, const unsigned short* __restrict__ eap24,
    const float* __restrict__ ew1l, const float* __restrict__ eb1l,
    const float* __restrict__ eb2l, const float* __restrict__ selfel,
    unsigned short* __restrict__ s1h, unsigned short* __restrict__ baseh, int GG)
{
  int tid = threadIdx.x;
  if ((int)blockIdx.x < GG){
    // ---------- gather path: half-wave per node, 2-node interleave (16 loads in flight) ----------
    int li = tid & 31;
    int c4 = li*4;
    float4 sf4 = *(const float4*)(selfel + c4);
    float4 e24 = *(const float4*)(eb2l + c4);
    int slot = blockIdx.x*8 + (tid>>5);
    const int NS = GG*8;
    for (int nA = slot; nA < NNODES; nA += 2*NS){
      int nB = nA + NS;
      bool hasB = (nB < NNODES);
      int rsA = rowptr[nA], reA = rowptr[nA+1];
      int rsB = 0, reB = 0;
      if (hasB){ rsB = rowptr[nB]; reB = rowptr[nB+1]; }
      f32x4 bA = (f32x4)0.f, bB = (f32x4)0.f;
      int cA = rsA, cB = rsB;
      while (cA < reA || cB < reB){
        bool dA = cA < reA, dB = cB < reB;
        uint2 hvA[8], hvB[8];
        float mA[8], mB[8];
        if (dA){
          #pragma unroll
          for (int p=0;p<8;++p){
            int e = cA + p; if (e > reA-1) e = reA-1;
            mA[p] = (cA + p < reA) ? 1.f : 0.f;
            int sp = srcp[e];
            hvA[p] = *(const uint2*)(hh + (size_t)sp*EMBD + c4);
          }
        }
        if (dB){
          #pragma unroll
          for (int p=0;p<8;++p){
            int e = cB + p; if (e > reB-1) e = reB-1;
            mB[p] = (cB + p < reB) ? 1.f : 0.f;
            int sp = srcp[e];
            hvB[p] = *(const uint2*)(hh + (size_t)sp*EMBD + c4);
          }
        }
        if (dA){
          #pragma unroll
          for (int p=0;p<8;++p){
            bA[0] = fmaf(mA[p], h2f((unsigned short)(hvA[p].x & 0xffffu)), bA[0]);
            bA[1] = fmaf(mA[p], h2f((unsigned short)(hvA[p].x >> 16)),     bA[1]);
            bA[2] = fmaf(mA[p], h2f((unsigned short)(hvA[p].y & 0xffffu)), bA[2]);
            bA[3] = fmaf(mA[p], h2f((unsigned short)(hvA[p].y >> 16)),     bA[3]);
          }
        }
        if (dB){
          #pragma unroll
          for (int p=0;p<8;++p){
            bB[0] = fmaf(mB[p], h2f((unsigned short)(hvB[p].x & 0xffffu)), bB[0]);
            bB[1] = fmaf(mB[p], h2f((unsigned short)(hvB[p].x >> 16)),     bB[1]);
            bB[2] = fmaf(mB[p], h2f((unsigned short)(hvB[p].y & 0xffffu)), bB[2]);
            bB[3] = fmaf(mB[p], h2f((unsigned short)(hvB[p].y >> 16)),     bB[3]);
          }
        }
        cA += 8; cB += 8;
      }
      {
        float deg = (float)(reA - rsA);
        uint2 hn = *(const uint2*)(hh + (size_t)nA*EMBD + c4);
        float ox = bA[0] + h2f((unsigned short)(hn.x & 0xffffu)) + sf4.x + deg*e24.x;
        float oy = bA[1] + h2f((unsigned short)(hn.x >> 16))     + sf4.y + deg*e24.y;
        float oz = bA[2] + h2f((unsigned short)(hn.y & 0xffffu)) + sf4.z + deg*e24.z;
        float ow = bA[3] + h2f((unsigned short)(hn.y >> 16))     + sf4.w + deg*e24.w;
        uint2 pk;
        pk.x = (unsigned)f2h(ox) | ((unsigned)f2h(oy) << 16);
        pk.y = (unsigned)f2h(oz) | ((unsigned)f2h(ow) << 16);
        *reinterpret_cast<uint2*>(baseh + (size_t)nA*EMBD + c4) = pk;
      }
      if (hasB){
        float deg = (float)(reB - rsB);
        uint2 hn = *(const uint2*)(hh + (size_t)nB*EMBD + c4);
        float ox = bB[0] + h2f((unsigned short)(hn.x & 0xffffu)) + sf4.x + deg*e24.x;
        float oy = bB[1] + h2f((unsigned short)(hn.x >> 16))     + sf4.y + deg*e24.y;
        float oz = bB[2] + h2f((unsigned short)(hn.y & 0xffffu)) + sf4.z + deg*e24.z;
        float ow = bB[3] + h2f((unsigned short)(hn.y >> 16))     + sf4.w + deg*e24.w;
        uint2 pk;
        pk.x = (unsigned)f2h(ox) | ((unsigned)f2h(oy) << 16);
        pk.y = (unsigned)f2h(oz) | ((unsigned)f2h(ow) << 16);
        *reinterpret_cast<uint2*>(baseh + (size_t)nB*EMBD + c4) = pk;
      }
    }
  } else {
    // ---------- S1 MFMA path (bf16 ew1 in regs, 2-node interleave), fp16 out ----------
    int lane = tid & 63;
    int lr = lane & 15, kb = lane >> 4;
    short8 bh[8];
    #pragma unroll
    for (int nf=0; nf<8; ++nf){
      int col = nf*16 + lr;
      ushort8 hh8;
      #pragma unroll
      for (int j=0;j<8;++j){
        int k = kb*8 + j;
        float v = 0.f;
        if (k < EDIM) v = ew1l[k*EMBD + col];
        else if (k == EDIM) v = eb1l[col];
        hh8[j] = f2b(v);
      }
      bh[nf] = *reinterpret_cast<short8*>(&hh8);
    }
    auto loadC = [&](int c0, int re)->short8{
      int cnt = re - c0;
      int idx = c0 + lr; if (idx > re-1) idx = re-1;
      short8 af = (short8)0;
      if (kb < 3){
        ushort8 t = *reinterpret_cast<const ushort8*>(eap24 + (size_t)idx*24 + kb*8);
        af = *reinterpret_cast<short8*>(&t);
      }
      if (lr >= cnt) af = (short8)0;
      return af;
    };
    const int GS = gridDim.x - GG;
    int wid = (blockIdx.x - GG)*4 + (tid>>6);
    const int NW = GS*4;
    for (int nA = wid; nA < NNODES; nA += 2*NW){
      int nB = nA + NW;
      bool hasB = (nB < NNODES);
      int rsA = rowptr[nA], reA = rowptr[nA+1];
      int rsB = 0, reB = 0;
      if (hasB){ rsB = rowptr[nB]; reB = rowptr[nB+1]; }
      float sA[8], sB[8];
      #pragma unroll
      for (int nf=0;nf<8;++nf){ sA[nf]=0.f; sB[nf]=0.f; }
      int cA = rsA, cB = rsB;
      while (cA < reA || cB < reB){
        bool dA = cA < reA, dB = cB < reB;
        short8 afA = (short8)0, afB = (short8)0;
        if (dA) afA = loadC(cA, reA);
        if (dB) afB = loadC(cB, reB);
        if (dA){
          #pragma unroll
          for (int nf=0;nf<8;++nf){
            f32x4 acc = (f32x4)0.f;
            acc = __builtin_amdgcn_mfma_f32_16x16x32_bf16(afA, bh[nf], acc, 0,0,0);
            #pragma unroll
            for (int j=0;j<4;++j){
              float v = acc[j];                  // leaky(v) = 0.55v + 0.45|v|
              sA[nf] = fmaf(0.55f, v, sA[nf]);
              sA[nf] = fmaf(0.45f, fabsf(v), sA[nf]);
            }
          }
        }
        if (dB){
          #pragma unroll
          for (int nf=0;nf<8;++nf){
            f32x4 acc = (f32x4)0.f;
            acc = __builtin_amdgcn_mfma_f32_16x16x32_bf16(afB, bh[nf], acc, 0,0,0);
            #pragma unroll
            for (int j=0;j<4;++j){
              float v = acc[j];
              sB[nf] = fmaf(0.55f, v, sB[nf]);
              sB[nf] = fmaf(0.45f, fabsf(v), sB[nf]);
            }
          }
        }
        cA += 16; cB += 16;
      }
      {
        #pragma unroll
        for (int nf=0;nf<8;++nf){
          float v = sA[nf];
          v += __shfl_xor(v, 16);
          v += __shfl_xor(v, 32);
          sA[nf] = v;
        }
        float va = sA[0], vb = sA[1];
        if (kb == 1){ va = sA[2]; vb = sA[3]; }
        if (kb == 2){ va = sA[4]; vb = sA[5]; }
        if (kb == 3){ va = sA[6]; vb = sA[7]; }
        s1h[(size_t)nA*EMBD + kb*32 + lr]      = f2h(va);
        s1h[(size_t)nA*EMBD + kb*32 + 16 + lr] = f2h(vb);
      }
      if (hasB){
        #pragma unroll
        for (int nf=0;nf<8;++nf){
          float v = sB[nf];
          v += __shfl_xor(v, 16);
          v += __shfl_xor(v, 32);
          sB[nf] = v;
        }
        float va = sB[0], vb = sB[1];
        if (kb == 1){ va = sB[2]; vb = sB[3]; }
        if (kb == 2){ va = sB[4]; vb = sB[5]; }
        if (kb == 3){ va = sB[6]; vb = sB[7]; }
        s1h[(size_t)nB*EMBD + kb*32 + lr]      = f2h(va);
        s1h[(size_t)nB*EMBD + kb*32 + 16 + lr] = f2h(vb);
      }
    }
  }
}

// ------------- tier-B combined edge dispatch (round-8/9 path, fp32 outputs) -------------
__global__ __launch_bounds__(256) void k_edge2(
    const unsigned short* __restrict__ hh, const int* __restrict__ rowptr,
    const int* __restrict__ srcp, const unsigned short* __restrict__ eap24,
    const float* __restrict__ ew1l, const float* __restrict__ eb1l,
    const float* __restrict__ eb2l, const float* __restrict__ selfel,
    float* __restrict__ S1, float* __restrict__ base, int GG)
{
  int tid = threadIdx.x;
  if ((int)blockIdx.x < GG){
    int li = tid & 31;
    int c4 = li*4;
    float4 sf4 = *(const float4*)(selfel + c4);
    float4 e24 = *(const float4*)(eb2l + c4);
    int slot = blockIdx.x*8 + (tid>>5);
    const int NS = GG*8;
    for (int node = slot; node < NNODES; node += NS){
      int rs = rowptr[node], re = rowptr[node+1];
      f32x4 b = (f32x4)0.f;
      for (int c0 = rs; c0 < re; c0 += 8){
        int cnt = re - c0;
        #pragma unroll
        for (int p=0;p<8;++p){
          int e = c0 + p; if (e > re-1) e = re-1;
          float m = (p < cnt) ? 1.f : 0.f;
          int sp = srcp[e];
          uint2 hv = *(const uint2*)(hh + (size_t)sp*EMBD + c4);
          b[0] = fmaf(m, h2f((unsigned short)(hv.x & 0xffffu)), b[0]);
          b[1] = fmaf(m, h2f((unsigned short)(hv.x >> 16)),     b[1]);
          b[2] = fmaf(m, h2f((unsigned short)(hv.y & 0xffffu)), b[2]);
          b[3] = fmaf(m, h2f((unsigned short)(hv.y >> 16)),     b[3]);
        }
      }
      float deg = (float)(re - rs);
      uint2 hn = *(const uint2*)(hh + (size_t)node*EMBD + c4);
      float4 o;
      o.x = b[0] + h2f((unsigned short)(hn.x & 0xffffu)) + sf4.x + deg*e24.x;
      o.y = b[1] + h2f((unsigned short)(hn.x >> 16))     + sf4.y + deg*e24.y;
      o.z = b[2] + h2f((unsigned short)(hn.y & 0xffffu)) + sf4.z + deg*e24.z;
      o.w = b[3] + h2f((unsigned short)(hn.y >> 16))     + sf4.w + deg*e24.w;
      *(float4*)(base + (size_t)node*EMBD + c4) = o;
    }
  } else {
    int lane = tid & 63;
    int lr = lane & 15, kb = lane >> 4;
    short8 bh[8];
    #pragma unroll
    for (int nf=0; nf<8; ++nf){
      int col = nf*16 + lr;
      ushort8 hh8;
      #pragma unroll
      for (int j=0;j<8;++j){
        int k = kb*8 + j;
        float v = 0.f;
        if (k < EDIM) v = ew1l[k*EMBD + col];
        else if (k == EDIM) v = eb1l[col];
        hh8[j] = f2b(v);
      }
      bh[nf] = *reinterpret_cast<short8*>(&hh8);
    }
    auto loadC = [&](int c0, int re)->short8{
      int cnt = re - c0;
      int idx = c0 + lr; if (idx > re-1) idx = re-1;
      short8 af = (short8)0;
      if (kb < 3){
        ushort8 t = *reinterpret_cast<const ushort8*>(eap24 + (size_t)idx*24 + kb*8);
        af = *reinterpret_cast<short8*>(&t);
      }
      if (lr >= cnt) af = (short8)0;
      return af;
    };
    const int GS = gridDim.x - GG;
    int wid = (blockIdx.x - GG)*4 + (tid>>6);
    const int NW = GS*4;
    for (int nA = wid; nA < NNODES; nA += 2*NW){
      int nB = nA + NW;
      bool hasB = (nB < NNODES);
      int rsA = rowptr[nA], reA = rowptr[nA+1];
      int rsB = 0, reB = 0;
      if (hasB){ rsB = rowptr[nB]; reB = rowptr[nB+1]; }
      float sA[8], sB[8];
      #pragma unroll
      for (int nf=0;nf<8;++nf){ sA[nf]=0.f; sB[nf]=0.f; }
      int cA = rsA, cB = rsB;
      while (cA < reA || cB < reB){
        bool dA = cA < reA, dB = cB < reB;
        short8 afA = (short8)0, afB = (short8)0;
        if (dA) afA = loadC(cA, reA);
        if (dB) afB = loadC(cB, reB);
        if (dA){
          #pragma unroll
          for (int nf=0;nf<8;++nf){
            f32x4 acc = (f32x4)0.f;
            acc = __builtin_amdgcn_mfma_f32_16x16x32_bf16(afA, bh[nf], acc, 0,0,0);
            #pragma unroll
            for (int j=0;j<4;++j){
              float v = acc[j];
              sA[nf] = fmaf(0.55f, v, sA[nf]);
              sA[nf] = fmaf(0.45f, fabsf(v), sA[nf]);
            }
          }
        }
        if (dB){
          #pragma unroll
          for (int nf=0;nf<8;++nf){
            f32x4 acc = (f32x4)0.f;
            acc = __builtin_amdgcn_mfma_f32_16x16x32_bf16(afB, bh[nf], acc, 0,0,0);
            #pragma unroll
            for (int j=0;j<4;++j){
              float v = acc[j];
              sB[nf] = fmaf(0.55f, v, sB[nf]);
              sB[nf] = fmaf(0.45f, fabsf(v), sB[nf]);
            }
          }
        }
        cA += 16; cB += 16;
      }
      {
        #pragma unroll
        for (int nf=0;nf<8;++nf){
          float v = sA[nf];
          v += __shfl_xor(v, 16);
          v += __shfl_xor(v, 32);
          sA[nf] = v;
        }
        float va = sA[0], vb = sA[1];
        if (kb == 1){ va = sA[2]; vb = sA[3]; }
        if (kb == 2){ va = sA[4]; vb = sA[5]; }
        if (kb == 3){ va = sA[6]; vb = sA[7]; }
        S1[(size_t)nA*EMBD + kb*32 + lr]      = va;
        S1[(size_t)nA*EMBD + kb*32 + 16 + lr] = vb;
      }
      if (hasB){
        #pragma unroll
        for (int nf=0;nf<8;++nf){
          float v = sB[nf];
          v += __shfl_xor(v, 16);
          v += __shfl_xor(v, 32);
          sB[nf] = v;
        }
        float va = sB[0], vb = sB[1];
        if (kb == 1){ va = sB[2]; vb = sB[3]; }
        if (kb == 2){ va = sB[4]; vb = sB[5]; }
        if (kb == 3){ va = sB[6]; vb = sB[7]; }
        S1[(size_t)nB*EMBD + kb*32 + lr]      = va;
        S1[(size_t)nB*EMBD + kb*32 + 16 + lr] = vb;
      }
    }
  }
}

// ------------- OLD edge kernel (tier-C fallback) -------------
__global__ __launch_bounds__(256) void k_edge(
    const float* __restrict__ h, const int* __restrict__ rowptr,
    const int* __restrict__ perm, const int* __restrict__ srcp,
    const float* __restrict__ edge_attr, const float* __restrict__ eaperm,
    const float* __restrict__ ew1l, const float* __restrict__ eb1l,
    const float* __restrict__ eb2l, const float* __restrict__ selfel,
    float* __restrict__ S1, float* __restrict__ base)
{
  __shared__ float w1s[EDIM*EMBD];
  __shared__ float b1s[EMBD];
  int tid = threadIdx.x;
  for (int i = tid; i < EDIM*EMBD; i += 256) w1s[i] = ew1l[i];
  if (tid < EMBD) b1s[tid] = eb1l[tid];
  __syncthreads();
  int lane = tid & 63;
  int node = blockIdx.x*4 + (tid >> 6);
  if (node >= NNODES) return;
  int rs = rowptr[node], re = rowptr[node+1];
  int c0 = lane*2;
  float s1x=0.f, s1y=0.f, bx=0.f, by=0.f;
  for (int i = rs; i < re; ++i){
    int s = __builtin_amdgcn_readfirstlane(srcp[i]);
    const float* ea;
    if (eaperm){
      ea = eaperm + (size_t)__builtin_amdgcn_readfirstlane(i)*EDIM;
    } else {
      ea = edge_attr + (size_t)__builtin_amdgcn_readfirstlane(perm[i])*EDIM;
    }
    float2 hs = *(const float2*)(h + (size_t)s*EMBD + c0);
    bx += hs.x; by += hs.y;
    float d0 = b1s[c0], d1 = b1s[c0+1];
    #pragma unroll
    for (int k=0;k<EDIM;++k){
      float av = ea[k];
      d0 += av * w1s[k*EMBD + c0];
      d1 += av * w1s[k*EMBD + c0 + 1];
    }
    s1x += leakyf(d0); s1y += leakyf(d1);
  }
  float deg = (float)(re - rs);
  float2 hv = *(const float2*)(h + (size_t)node*EMBD + c0);
  *(float2*)(S1 + (size_t)node*EMBD + c0) = make_float2(s1x, s1y);
  float bvx = bx + hv.x + selfel[c0]   + deg*eb2l[c0];
  float bvy = by + hv.y + selfel[c0+1] + deg*eb2l[c0+1];
  *(float2*)(base + (size_t)node*EMBD + c0) = make_float2(bvx, bvy);
}

// ------------- MFMA GEMM: C = act(A[M,K] @ B + bias), split-bf16 precision -------------
// A sources: fp32 (Af/A1, CONCAT), bf16 (Ab), or fp16 (Afh; with CONCAT: Afh first half, Afh2 second).
template<int BN, int WGM, int WGN, bool ALO, bool BLO, int ACT, bool STATS, bool OBF16,
         bool CONCAT, bool KCHK, bool ABF16, bool AH16>
__global__ __launch_bounds__(512) void k_mgemm(
    const float* __restrict__ Af, const float* __restrict__ A1,
    const __hip_bfloat16* __restrict__ Ab,
    const unsigned short* __restrict__ Afh, const unsigned short* __restrict__ Afh2,
    int M, int Kreal, int Kpad, int lda,
    const __hip_bfloat16* __restrict__ Bp,
    const float* __restrict__ bias,
    float* __restrict__ Cf, __hip_bfloat16* __restrict__ Cb, int ldc,
    float* __restrict__ stats, unsigned short* __restrict__ Ch)
{
  static_assert(WGM*WGN == 8, "8 waves");
  constexpr int BM = 128;
  constexpr int MF = BM/(16*WGM);
  constexpr int NF = BN/(16*WGN);
  constexpr int LDS_ROW = 40;
  __shared__ __align__(16) unsigned short Ah[BM*LDS_ROW];
  __shared__ __align__(16) unsigned short Al[ALO ? BM*LDS_ROW : 8];
  __shared__ float ssum[STATS ? BN : 4];
  __shared__ float ssq [STATS ? BN : 4];

  int tid = threadIdx.x;
  int row0 = blockIdx.x*BM;
  int w = tid >> 6, lane = tid & 63;
  int wm = w / WGN, wn = w % WGN;
  int lr = lane & 15, kb = lane >> 4;
  int wrow = wm*MF*16, wcol = wn*NF*16;

  if (STATS && tid < BN){ ssum[tid] = 0.f; ssq[tid] = 0.f; }

  f32x4 acc[MF][NF];
  #pragma unroll
  for (int a=0;a<MF;++a)
    #pragma unroll
    for (int b=0;b<NF;++b) acc[a][b] = (f32x4)0.f;

  const size_t planeSz = (size_t)Kpad*BN;
  int sr = tid >> 2;
  int skq = (tid & 3)*8;
  int grow = row0 + sr;
  const int KS = Kpad >> 5;

  for (int ks = 0; ks < KS; ++ks){
    int k0 = ks << 5;
    int kg = k0 + skq;
    ushort8 hv, lv;
    if (ABF16){
      short8 raw = (short8)0;
      if (grow < M) raw = *reinterpret_cast<const short8*>((const unsigned short*)Ab + (size_t)grow*lda + kg);
      hv = *reinterpret_cast<ushort8*>(&raw);
    } else {
      float v[8];
      if (AH16){
        const unsigned short* s16;
        if (CONCAT) s16 = (kg < EMBD) ? (Afh + (size_t)grow*EMBD + kg)
                                      : (Afh2 + (size_t)grow*EMBD + (kg - EMBD));
        else        s16 = Afh + (size_t)grow*lda + kg;
        ushort8 raw = (ushort8)0;
        if (grow < M) raw = *reinterpret_cast<const ushort8*>(s16);
        #pragma unroll
        for (int i=0;i<8;++i) v[i] = h2f(raw[i]);
      } else if (KCHK){
        #pragma unroll
        for (int i=0;i<8;++i)
          v[i] = (grow < M && kg+i < Kreal) ? Af[(size_t)grow*lda + kg + i] : 0.f;
      } else {
        const float* s;
        if (CONCAT) s = (kg < EMBD) ? (Af + (size_t)grow*lda + kg) : (A1 + (size_t)grow*lda + (kg - EMBD));
        else        s = Af + (size_t)grow*lda + kg;
        float4 p0 = make_float4(0,0,0,0), p1 = make_float4(0,0,0,0);
        if (grow < M){ p0 = *(const float4*)s; p1 = *(const float4*)(s+4); }
        v[0]=p0.x; v[1]=p0.y; v[2]=p0.z; v[3]=p0.w;
        v[4]=p1.x; v[5]=p1.y; v[6]=p1.z; v[7]=p1.w;
      }
      #pragma unroll
      for (int i=0;i<8;++i){
        unsigned short h16 = f2b(v[i]);
        hv[i] = h16;
        if (ALO) lv[i] = f2b(v[i] - b2f(h16));
      }
    }
    __syncthreads();
    *reinterpret_cast<ushort8*>(&Ah[sr*LDS_ROW + skq]) = hv;
    if (ALO && !ABF16) *reinterpret_cast<ushort8*>(&Al[sr*LDS_ROW + skq]) = lv;
    __syncthreads();

    short8 ah[MF], al[MF];
    #pragma unroll
    for (int mf=0; mf<MF; ++mf){
      int r = (wrow + mf*16 + lr)*LDS_ROW + kb*8;
      ah[mf] = *reinterpret_cast<const short8*>(&Ah[r]);
      if (ALO) al[mf] = *reinterpret_cast<const short8*>(&Al[r]);
    }
    const unsigned short* bb = (const unsigned short*)Bp + (size_t)ks*BN*32;
    short8 bh[NF], blv[NF];
    #pragma unroll
    for (int nf=0; nf<NF; ++nf){
      size_t off = (size_t)(wcol + nf*16 + lr)*32 + kb*8;
      bh[nf] = *reinterpret_cast<const short8*>(bb + off);
      if (BLO) blv[nf] = *reinterpret_cast<const short8*>(bb + planeSz + off);
    }
    #pragma unroll
    for (int mf=0; mf<MF; ++mf){
      #pragma unroll
      for (int nf=0; nf<NF; ++nf){
        acc[mf][nf] = __builtin_amdgcn_mfma_f32_16x16x32_bf16(ah[mf], bh[nf], acc[mf][nf], 0, 0, 0);
        if (BLO)
          acc[mf][nf] = __builtin_amdgcn_mfma_f32_16x16x32_bf16(ah[mf], blv[nf], acc[mf][nf], 0, 0, 0);
        if (ALO)
          acc[mf][nf] = __builtin_amdgcn_mfma_f32_16x16x32_bf16(al[mf], bh[nf], acc[mf][nf], 0, 0, 0);
      }
    }
  }

  float bcol[NF];
  #pragma unroll
  for (int nf=0; nf<NF; ++nf) bcol[nf] = bias ? bias[wcol + nf*16 + lr] : 0.f;
  float s[NF], sq[NF];
  #pragma unroll
  for (int nf=0; nf<NF; ++nf){ s[nf]=0.f; sq[nf]=0.f; }

  #pragma unroll
  for (int mf=0; mf<MF; ++mf){
    #pragma unroll
    for (int j=0; j<4; ++j){
      int r = row0 + wrow + mf*16 + kb*4 + j;
      if (r < M){
        #pragma unroll
        for (int nf=0; nf<NF; ++nf){
          int c = wcol + nf*16 + lr;
          float v = acc[mf][nf][j] + bcol[nf];
          if (ACT == 1) v = leakyf(v);
          if (ACT == 2) v = fmaxf(v, 0.f);
          if (OBF16) Cb[(size_t)r*ldc + c] = __float2bfloat16(v);
          else if (Cf) Cf[(size_t)r*ldc + c] = v;
          if (Ch) Ch[(size_t)r*ldc + c] = f2h(v);
          if (STATS){ s[nf] += v; sq[nf] += v*v; }
        }
      }
    }
  }
  if (STATS){
    #pragma unroll
    for (int nf=0; nf<NF; ++nf){
      atomicAdd(&ssum[wcol + nf*16 + lr], s[nf]);
      atomicAdd(&ssq [wcol + nf*16 + lr], sq[nf]);
    }
    __syncthreads();
    if (tid < BN){
      atomicAdd(&stats[tid], ssum[tid]);
      atomicAdd(&stats[BN + tid], ssq[tid]);
    }
  }
}

// ------------- BatchNorm normalize (+optional relu; fp32 and/or fp16 outputs) -------------
__global__ __launch_bounds__(256) void k_bn(const float* __restrict__ hh, const float* __restrict__ stats,
                                            const float* __restrict__ gamma, const float* __restrict__ beta,
                                            float* __restrict__ out, unsigned short* __restrict__ outh,
                                            int dorelu){
  int idx = blockIdx.x*256 + threadIdx.x;
  if (idx >= NNODES*(EMBD/4)) return;
  int c0 = (idx & (EMBD/4 - 1)) * 4;
  float4 v = *(const float4*)(hh + (size_t)idx*4);
  float o[4] = {v.x, v.y, v.z, v.w};
  const float invN = 1.f / (float)NNODES;
  #pragma unroll
  for (int i=0;i<4;++i){
    int c = c0 + i;
    float mean = stats[c] * invN;
    float var  = stats[EMBD + c] * invN - mean*mean;
    float inv  = rsqrtf(fmaxf(var, 0.f) + BNEPS);
    float y = (o[i] - mean) * inv * gamma[c] + beta[c];
    if (dorelu) y = fmaxf(y, 0.f);
    o[i] = y;
  }
  if (out) *(float4*)(out + (size_t)idx*4) = make_float4(o[0],o[1],o[2],o[3]);
  if (outh){
    uint2 pk;
    pk.x = (unsigned)f2h(o[0]) | ((unsigned)f2h(o[1]) << 16);
    pk.y = (unsigned)f2h(o[2]) | ((unsigned)f2h(o[3]) << 16);
    *reinterpret_cast<uint2*>(outh + (size_t)idx*4) = pk;
  }
}

// ---------------- launcher ----------------
extern "C" void kernel_launch(void* const* d_in, const int* in_sizes, int n_in,
                              void* d_out, int out_size, void* d_ws, size_t ws_size,
                              hipStream_t stream)
{
  const float* x   = (const float*)d_in[0];
  const float* ea  = (const float*)d_in[1];
  const float* iw1 = (const float*)d_in[2];
  const float* ib1 = (const float*)d_in[3];
  const float* iw2 = (const float*)d_in[4];
  const float* ib2 = (const float*)d_in[5];
  const float* ew1 = (const float*)d_in[6];
  const float* eb1 = (const float*)d_in[7];
  const float* ew2 = (const float*)d_in[8];
  const float* eb2 = (const float*)d_in[9];
  const float* mw1 = (const float*)d_in[10];
  const float* mb1 = (const float*)d_in[11];
  const float* mw2 = (const float*)d_in[12];
  const float* mb2 = (const float*)d_in[13];
  const float* gamma = (const float*)d_in[14];
  const float* beta  = (const float*)d_in[15];
  const int* eidx = (const int*)d_in[16];
  const int* srcI = eidx;
  const int* dstI = eidx + NEDGES;

  char* p = (char*)d_ws;
  auto alloc = [&](size_t bytes)->char*{
    char* r = p; p += (bytes + 255) & ~(size_t)255; return r;
  };
  float* S1    = (float*)alloc((size_t)NNODES*EMBD*4);
  float* base  = (float*)alloc((size_t)NNODES*EMBD*4);
  __hip_bfloat16* tbuf = (__hip_bfloat16*)alloc((size_t)NNODES*2*EMBD*2);
  int* perm   = (int*)alloc((size_t)NEDGES*4);     // == einv in new path
  int* srcp   = (int*)alloc((size_t)NEDGES*4);
  int* rowptr = (int*)alloc((size_t)(NNODES+1)*4);
  int* cursor = (int*)alloc((size_t)NNODES*4);
  int* bsum   = (int*)alloc(4096);
  int* boff   = (int*)alloc(4096);
  float* selfe = (float*)alloc(NLAYER*EMBD*4);
  float* stats = (float*)alloc(2*EMBD*4);
  float* wc    = (float*)alloc((size_t)NLAYER*EMBD*2*EMBD*4);
  __hip_bfloat16* Bi1 = (__hip_bfloat16*)alloc((size_t)192*EMBD*2*2);
  __hip_bfloat16* Bi2 = (__hip_bfloat16*)alloc((size_t)EMBD*EMBD*2*2);
  __hip_bfloat16* B1  = (__hip_bfloat16*)alloc((size_t)NLAYER*256*256*2*2);
  __hip_bfloat16* B2  = (__hip_bfloat16*)alloc((size_t)NLAYER*256*EMBD*2*2);
  size_t used = (size_t)(p - (char*)d_ws);

  const size_t szEap  = (size_t)NEDGES*24*2;
  const size_t szHh   = (size_t)NNODES*EMBD*2;
  const size_t szH16  = (size_t)NNODES*EMBD*2;
  const size_t szHbuf = (size_t)NNODES*EMBD*4;

  bool tierN = (ws_size >= used + szEap + szHh + 2*szH16 + 1024);   // fp16 S1/base path
  bool tierB = !tierN && (ws_size >= used + szEap + szHh + 512);
  unsigned short* eap24 = nullptr;
  unsigned short* hh16 = nullptr;
  unsigned short* s1h = nullptr;
  unsigned short* baseh = nullptr;
  float* hbuf = nullptr;
  float* eaperm = nullptr;
  if (tierN){
    eap24 = (unsigned short*)alloc(szEap);
    hh16  = (unsigned short*)alloc(szHh);
    s1h   = (unsigned short*)alloc(szH16);
    baseh = (unsigned short*)alloc(szH16);
  } else if (tierB){
    eap24 = (unsigned short*)alloc(szEap);
    hh16  = (unsigned short*)alloc(szHh);
  } else {
    hbuf = (float*)alloc(szHbuf);
    used = (size_t)(p - (char*)d_ws);
    if (ws_size >= used + (size_t)NEDGES*EDIM*4 + 256)
      eaperm = (float*)alloc((size_t)NEDGES*EDIM*4);
  }
  bool use_new = tierN || tierB;

  // ---- CSR build ----
  hipMemsetAsync(cursor, 0, (size_t)NNODES*4, stream);
  k_hist<<<(NEDGES+255)/256, 256, 0, stream>>>(dstI, cursor);
  int nb = (NNODES+255)/256;
  k_scan1<<<nb, 256, 0, stream>>>(cursor, rowptr, bsum);
  k_scan2<<<1, 512, 0, stream>>>(bsum, boff, nb);
  k_scan3<<<(NNODES+255)/256, 256, 0, stream>>>(rowptr, boff);
  k_curcopy<<<(NNODES+255)/256, 256, 0, stream>>>(rowptr, cursor);
  if (use_new){
    k_fill_pos<<<(NEDGES+255)/256, 256, 0, stream>>>(dstI, cursor, perm);
    k_fill_ea<<<(NEDGES+255)/256, 256, 0, stream>>>(perm, srcI, ea, srcp, eap24);
  } else {
    k_fill<<<(NEDGES+255)/256, 256, 0, stream>>>(srcI, dstI, ea, cursor, perm, srcp, eaperm);
  }
  k_selfe<<<NLAYER, EMBD, 0, stream>>>(eb1, ew2, eb2, selfe);

  // ---- weight prep ----
  k_wc<<<(NLAYER*EMBD*2*EMBD)/256, 256, 0, stream>>>(ew2, mw1, wc);
  k_pack<<<(192*EMBD+255)/256, 256, 0, stream>>>(iw1, XDIM, iw1, XDIM, 192, EMBD, Bi1);
  k_pack<<<(EMBD*EMBD+255)/256, 256, 0, stream>>>(iw2, EMBD, iw2, EMBD, EMBD, EMBD, Bi2);
  for (int l=0; l<NLAYER; ++l){
    k_pack<<<(256*256+255)/256, 256, 0, stream>>>(
        wc + (size_t)l*EMBD*2*EMBD, EMBD, mw1 + (size_t)l*EMBD*2*EMBD, 256, 256, 256,
        B1 + (size_t)l*256*256*2);
    k_pack<<<(256*EMBD+255)/256, 256, 0, stream>>>(
        mw2 + (size_t)l*2*EMBD*EMBD, 256, mw2, 256, 256, EMBD,
        B2 + (size_t)l*256*EMBD*2);
  }

  const int gx = (NNODES + 127)/128;

  // ---- input MLP ----
  k_mgemm<128,4,2, true,true,1,false,false,false,true ,false,false><<<gx, 512, 0, stream>>>(
      x, nullptr, nullptr, nullptr, nullptr, NNODES, XDIM, 192, XDIM, Bi1, ib1,
      S1, nullptr, EMBD, nullptr, nullptr);
  k_mgemm<128,4,2, true,true,0,false,false,false,false,false,false><<<gx, 512, 0, stream>>>(
      S1, nullptr, nullptr, nullptr, nullptr, NNODES, EMBD, EMBD, EMBD, Bi2, ib2,
      use_new ? nullptr : hbuf, nullptr, EMBD, nullptr, use_new ? hh16 : nullptr);

  for (int l=0; l<NLAYER; ++l){
    hipMemsetAsync(stats, 0, 2*EMBD*4, stream);
    if (tierN){
      k_edge4<<<2048, 256, 0, stream>>>(
          hh16, rowptr, srcp, eap24,
          ew1 + (size_t)l*EDIM*EMBD, eb1 + l*EMBD, eb2 + l*EMBD, selfe + l*EMBD,
          s1h, baseh, 1664);
      // t = relu([s1h|baseh](fp16) @ [Wc;mw1] + mb1) -> bf16 [N,256]  (A split hi+lo)
      k_mgemm<256,2,4, true,true,2,false,true ,true ,false,false,true ><<<gx, 512, 0, stream>>>(
          nullptr, nullptr, nullptr, s1h, baseh, NNODES, 256, 256, EMBD,
          B1 + (size_t)l*256*256*2, mb1 + l*2*EMBD, nullptr, tbuf, 2*EMBD, nullptr, nullptr);
    } else if (tierB){
      k_edge2<<<2048, 256, 0, stream>>>(
          hh16, rowptr, srcp, eap24,
          ew1 + (size_t)l*EDIM*EMBD, eb1 + l*EMBD, eb2 + l*EMBD, selfe + l*EMBD,
          S1, base, 1408);
      k_mgemm<256,2,4, true,true,2,false,true ,true ,false,false,false><<<gx, 512, 0, stream>>>(
          S1, base, nullptr, nullptr, nullptr, NNODES, 256, 256, EMBD,
          B1 + (size_t)l*256*256*2, mb1 + l*2*EMBD, nullptr, tbuf, 2*EMBD, nullptr, nullptr);
    } else {
      k_edge<<<NNODES/4, 256, 0, stream>>>(
          hbuf, rowptr, perm, srcp, ea, eaperm,
          ew1 + (size_t)l*EDIM*EMBD, eb1 + l*EMBD, eb2 + l*EMBD, selfe + l*EMBD,
          S1, base);
      k_mgemm<256,2,4, true,true,2,false,true ,true ,false,false,false><<<gx, 512, 0, stream>>>(
          S1, base, nullptr, nullptr, nullptr, NNODES, 256, 256, EMBD,
          B1 + (size_t)l*256*256*2, mb1 + l*2*EMBD, nullptr, tbuf, 2*EMBD, nullptr, nullptr);
    }
    // hh (into S1) = t @ mw2 + mb2, fused BN stats  (bf16 A, bf16-hi B only)
    k_mgemm<128,4,2, false,false,0,true ,false,false,false,true ,false><<<gx, 512, 0, stream>>>(
        nullptr, nullptr, tbuf, nullptr, nullptr, NNODES, 256, 256, 2*EMBD,
        B2 + (size_t)l*256*EMBD*2, mb2 + l*EMBD, S1, nullptr, EMBD, stats, nullptr);
    // BN normalize: intermediate layers -> fp16 h only; last layer -> fp32 d_out
    float* outp; unsigned short* outh;
    if (l == NLAYER-1){ outp = (float*)d_out; outh = nullptr; }
    else if (use_new) { outp = nullptr;       outh = hh16;    }
    else              { outp = hbuf;          outh = nullptr; }
    k_bn<<<(NNODES*(EMBD/4)+255)/256, 256, 0, stream>>>(
        S1, stats, gamma + l*EMBD, beta + l*EMBD, outp, outh, (l < NLAYER-1) ? 1 : 0);
  }
}

// Round 16
// 1898.971 us; speedup vs baseline: 1.0700x; 1.0700x over previous
//
#include <hip/hip_runtime.h>
#include <hip/hip_bf16.h>
#include <hip/hip_fp16.h>
#include <cstdint>
#include <cstddef>

#define NNODES 100000
#define NEDGES 1600000
#define EMBD 128
#define NLAYER 5
#define XDIM 178
#define EDIM 18
#define BNEPS 1e-5f

typedef __attribute__((ext_vector_type(8))) short short8;
typedef __attribute__((ext_vector_type(8))) unsigned short ushort8;
typedef __attribute__((ext_vector_type(4))) float f32x4;

static __device__ __forceinline__ float leakyf(float v){ return v > 0.f ? v : 0.1f*v; }
static __device__ __forceinline__ unsigned short f2b(float v){
  __hip_bfloat16 b = __float2bfloat16(v);
  return *reinterpret_cast<unsigned short*>(&b);
}
static __device__ __forceinline__ float b2f(unsigned short u){
  __hip_bfloat16 b = *reinterpret_cast<__hip_bfloat16*>(&u);
  return __bfloat162float(b);
}
static __device__ __forceinline__ unsigned short f2h(float v){
  __half h = __float2half(v);
  return *reinterpret_cast<unsigned short*>(&h);
}
static __device__ __forceinline__ float h2f(unsigned short u){
  __half h = *reinterpret_cast<__half*>(&u);
  return __half2float(h);
}

// ---------------- CSR build ----------------
__global__ __launch_bounds__(256) void k_hist(const int* __restrict__ dst, int* __restrict__ cnt){
  int e = blockIdx.x*256 + threadIdx.x;
  if (e < NEDGES) atomicAdd(&cnt[dst[e]], 1);
}

__global__ __launch_bounds__(256) void k_scan1(const int* __restrict__ cnt, int* __restrict__ rowptr,
                                               int* __restrict__ bsum){
  __shared__ int s[256];
  int t = threadIdx.x, i = blockIdx.x*256 + t;
  int v = (i < NNODES) ? cnt[i] : 0;
  s[t] = v; __syncthreads();
  for (int off=1; off<256; off<<=1){
    int x = (t>=off) ? s[t-off] : 0; __syncthreads();
    s[t] += x; __syncthreads();
  }
  if (i < NNODES) rowptr[i+1] = s[t];
  if (t == 255) bsum[blockIdx.x] = s[t];
}

__global__ __launch_bounds__(512) void k_scan2(const int* __restrict__ bsum, int* __restrict__ boff, int nb){
  __shared__ int s[512];
  int t = threadIdx.x;
  int v = (t < nb) ? bsum[t] : 0;
  s[t] = v; __syncthreads();
  for (int off=1; off<512; off<<=1){
    int x = (t>=off) ? s[t-off] : 0; __syncthreads();
    s[t] += x; __syncthreads();
  }
  if (t < nb) boff[t] = s[t] - v;
}

__global__ __launch_bounds__(256) void k_scan3(int* __restrict__ rowptr, const int* __restrict__ boff){
  int i = blockIdx.x*256 + threadIdx.x;
  if (i < NNODES) rowptr[i+1] += boff[i>>8];
  if (i == 0) rowptr[0] = 0;
}

__global__ __launch_bounds__(256) void k_curcopy(const int* __restrict__ rowptr, int* __restrict__ cursor){
  int i = blockIdx.x*256 + threadIdx.x;
  if (i < NNODES) cursor[i] = rowptr[i];
}

// pass A: position + inverse permutation only (4B scatter into L2-resident 6.4MB array)
__global__ __launch_bounds__(256) void k_fill_pos(const int* __restrict__ dst, int* __restrict__ cursor,
                                                  int* __restrict__ einv){
  int e = blockIdx.x*256 + threadIdx.x;
  if (e >= NEDGES) return;
  int pos = atomicAdd(&cursor[dst[e]], 1);
  einv[pos] = e;
}

// pass B: pos-coalesced; random READS of ea rows; coalesced writes of eap24+srcp
__global__ __launch_bounds__(256) void k_fill_ea(const int* __restrict__ einv, const int* __restrict__ src,
                                                 const float* __restrict__ ea,
                                                 int* __restrict__ srcp, unsigned short* __restrict__ eap24){
  int pos = blockIdx.x*256 + threadIdx.x;
  if (pos >= NEDGES) return;
  int e = einv[pos];
  srcp[pos] = src[e];
  const float* a = ea + (size_t)e*EDIM;
  float v[18];
  #pragma unroll
  for (int k=0;k<9;++k){
    float2 t = *(const float2*)(a + 2*k);
    v[2*k] = t.x; v[2*k+1] = t.y;
  }
  ushort8 r0, r1, r2;
  #pragma unroll
  for (int k=0;k<8;++k) r0[k] = f2b(v[k]);
  #pragma unroll
  for (int k=0;k<8;++k) r1[k] = f2b(v[8+k]);
  #pragma unroll
  for (int k=0;k<8;++k) r2[k] = 0;
  r2[0] = f2b(v[16]); r2[1] = f2b(v[17]);
  r2[2] = 0x3F80;   // bf16 1.0 at k=18 -> bias slot
  unsigned short* o = eap24 + (size_t)pos*24;
  *reinterpret_cast<ushort8*>(o)      = r0;
  *reinterpret_cast<ushort8*>(o + 8)  = r1;
  *reinterpret_cast<ushort8*>(o + 16) = r2;
}

// old-path fill (fallback)
__global__ __launch_bounds__(256) void k_fill(const int* __restrict__ src, const int* __restrict__ dst,
                                              const float* __restrict__ ea, int* __restrict__ cursor,
                                              int* __restrict__ perm, int* __restrict__ srcp,
                                              float* __restrict__ eap){
  int e = blockIdx.x*256 + threadIdx.x;
  if (e >= NEDGES) return;
  int pos = atomicAdd(&cursor[dst[e]], 1);
  perm[pos] = e;
  srcp[pos] = src[e];
  if (eap){
    const float* a = ea + (size_t)e*EDIM;
    float* o = eap + (size_t)pos*EDIM;
    #pragma unroll
    for (int k=0;k<EDIM;++k) o[k] = a[k];
  }
}

// self_e[l] = leaky(eb1[l]) @ ew2[l] + eb2[l]
__global__ __launch_bounds__(128) void k_selfe(const float* __restrict__ eb1, const float* __restrict__ ew2,
                                               const float* __restrict__ eb2, float* __restrict__ selfe){
  int l = blockIdx.x, c = threadIdx.x;
  const float* b1 = eb1 + l*EMBD;
  const float* w2 = ew2 + (size_t)l*EMBD*EMBD;
  float acc = eb2[l*EMBD + c];
  for (int j=0;j<EMBD;++j) acc += leakyf(b1[j]) * w2[j*EMBD + c];
  selfe[l*EMBD + c] = acc;
}

// Wc[l] = ew2[l] @ mw1[l]  ([128][256] fp32)
__global__ __launch_bounds__(256) void k_wc(const float* __restrict__ ew2, const float* __restrict__ mw1,
                                            float* __restrict__ wc){
  int idx = blockIdx.x*256 + threadIdx.x;       // 5*128*256
  int l = idx >> 15, rem = idx & 32767;
  int i = rem >> 8, n = rem & 255;
  const float* e = ew2 + (size_t)l*EMBD*EMBD + i*EMBD;
  const float* m = mw1 + (size_t)l*EMBD*2*EMBD + n;
  float acc = 0.f;
  #pragma unroll 4
  for (int j=0;j<EMBD;++j) acc += e[j]*m[(size_t)j*2*EMBD];
  wc[idx] = acc;
}

// pack B [Kpad x N] into hi/lo bf16 planes laid out [ks][n][kk]
__global__ __launch_bounds__(256) void k_pack(const float* __restrict__ s1, int rows1,
                                              const float* __restrict__ s2, int Kreal,
                                              int Kpad, int N, __hip_bfloat16* __restrict__ out){
  int idx = blockIdx.x*256 + threadIdx.x;
  if (idx >= Kpad*N) return;
  int k = idx / N, n = idx - k*N;
  float v = 0.f;
  if (k < rows1) v = s1[(size_t)k*N + n];
  else if (k < Kreal) v = s2[(size_t)(k-rows1)*N + n];
  unsigned short hi = f2b(v);
  unsigned short lo = f2b(v - b2f(hi));
  size_t o = (size_t)(k>>5)*N*32 + (size_t)n*32 + (k&31);
  unsigned short* po = (unsigned short*)out;
  po[o] = hi;
  po[(size_t)Kpad*N + o] = lo;
}

// ------------- tier-N combined edge dispatch: 2-node-interleaved gather + S1 MFMA, fp16 outputs -------------
__global__ __launch_bounds__(256) void k_edge4(
    const unsigned short* __restrict__ hh, const int* __restrict__ rowptr,
    const int* __restrict__ srcp, const unsigned short* __restrict__ eap24,
    const float* __restrict__ ew1l, const float* __restrict__ eb1l,
    const float* __restrict__ eb2l, const float* __restrict__ selfel,
    unsigned short* __restrict__ s1h, unsigned short* __restrict__ baseh, int GG)
{
  int tid = threadIdx.x;
  if ((int)blockIdx.x < GG){
    // ---------- gather path: half-wave per node, 2-node interleave (16 loads in flight) ----------
    int li = tid & 31;
    int c4 = li*4;
    float4 sf4 = *(const float4*)(selfel + c4);
    float4 e24 = *(const float4*)(eb2l + c4);
    int slot = blockIdx.x*8 + (tid>>5);
    const int NS = GG*8;
    for (int nA = slot; nA < NNODES; nA += 2*NS){
      int nB = nA + NS;
      bool hasB = (nB < NNODES);
      int rsA = rowptr[nA], reA = rowptr[nA+1];
      int rsB = 0, reB = 0;
      if (hasB){ rsB = rowptr[nB]; reB = rowptr[nB+1]; }
      f32x4 bA = (f32x4)0.f, bB = (f32x4)0.f;
      int cA = rsA, cB = rsB;
      while (cA < reA || cB < reB){
        bool dA = cA < reA, dB = cB < reB;
        uint2 hvA[8], hvB[8];
        float mA[8], mB[8];
        if (dA){
          #pragma unroll
          for (int p=0;p<8;++p){
            int e = cA + p; if (e > reA-1) e = reA-1;
            mA[p] = (cA + p < reA) ? 1.f : 0.f;
            int sp = srcp[e];
            hvA[p] = *(const uint2*)(hh + (size_t)sp*EMBD + c4);
          }
        }
        if (dB){
          #pragma unroll
          for (int p=0;p<8;++p){
            int e = cB + p; if (e > reB-1) e = reB-1;
            mB[p] = (cB + p < reB) ? 1.f : 0.f;
            int sp = srcp[e];
            hvB[p] = *(const uint2*)(hh + (size_t)sp*EMBD + c4);
          }
        }
        if (dA){
          #pragma unroll
          for (int p=0;p<8;++p){
            bA[0] = fmaf(mA[p], h2f((unsigned short)(hvA[p].x & 0xffffu)), bA[0]);
            bA[1] = fmaf(mA[p], h2f((unsigned short)(hvA[p].x >> 16)),     bA[1]);
            bA[2] = fmaf(mA[p], h2f((unsigned short)(hvA[p].y & 0xffffu)), bA[2]);
            bA[3] = fmaf(mA[p], h2f((unsigned short)(hvA[p].y >> 16)),     bA[3]);
          }
        }
        if (dB){
          #pragma unroll
          for (int p=0;p<8;++p){
            bB[0] = fmaf(mB[p], h2f((unsigned short)(hvB[p].x & 0xffffu)), bB[0]);
            bB[1] = fmaf(mB[p], h2f((unsigned short)(hvB[p].x >> 16)),     bB[1]);
            bB[2] = fmaf(mB[p], h2f((unsigned short)(hvB[p].y & 0xffffu)), bB[2]);
            bB[3] = fmaf(mB[p], h2f((unsigned short)(hvB[p].y >> 16)),     bB[3]);
          }
        }
        cA += 8; cB += 8;
      }
      {
        float deg = (float)(reA - rsA);
        uint2 hn = *(const uint2*)(hh + (size_t)nA*EMBD + c4);
        float ox = bA[0] + h2f((unsigned short)(hn.x & 0xffffu)) + sf4.x + deg*e24.x;
        float oy = bA[1] + h2f((unsigned short)(hn.x >> 16))     + sf4.y + deg*e24.y;
        float oz = bA[2] + h2f((unsigned short)(hn.y & 0xffffu)) + sf4.z + deg*e24.z;
        float ow = bA[3] + h2f((unsigned short)(hn.y >> 16))     + sf4.w + deg*e24.w;
        uint2 pk;
        pk.x = (unsigned)f2h(ox) | ((unsigned)f2h(oy) << 16);
        pk.y = (unsigned)f2h(oz) | ((unsigned)f2h(ow) << 16);
        *reinterpret_cast<uint2*>(baseh + (size_t)nA*EMBD + c4) = pk;
      }
      if (hasB){
        float deg = (float)(reB - rsB);
        uint2 hn = *(const uint2*)(hh + (size_t)nB*EMBD + c4);
        float ox = bB[0] + h2f((unsigned short)(hn.x & 0xffffu)) + sf4.x + deg*e24.x;
        float oy = bB[1] + h2f((unsigned short)(hn.x >> 16))     + sf4.y + deg*e24.y;
        float oz = bB[2] + h2f((unsigned short)(hn.y & 0xffffu)) + sf4.z + deg*e24.z;
        float ow = bB[3] + h2f((unsigned short)(hn.y >> 16))     + sf4.w + deg*e24.w;
        uint2 pk;
        pk.x = (unsigned)f2h(ox) | ((unsigned)f2h(oy) << 16);
        pk.y = (unsigned)f2h(oz) | ((unsigned)f2h(ow) << 16);
        *reinterpret_cast<uint2*>(baseh + (size_t)nB*EMBD + c4) = pk;
      }
    }
  } else {
    // ---------- S1 MFMA path (bf16 ew1 in regs, 2-node interleave), fp16 out ----------
    int lane = tid & 63;
    int lr = lane & 15, kb = lane >> 4;
    short8 bh[8];
    #pragma unroll
    for (int nf=0; nf<8; ++nf){
      int col = nf*16 + lr;
      ushort8 hh8;
      #pragma unroll
      for (int j=0;j<8;++j){
        int k = kb*8 + j;
        float v = 0.f;
        if (k < EDIM) v = ew1l[k*EMBD + col];
        else if (k == EDIM) v = eb1l[col];
        hh8[j] = f2b(v);
      }
      bh[nf] = *reinterpret_cast<short8*>(&hh8);
    }
    auto loadC = [&](int c0, int re)->short8{
      int cnt = re - c0;
      int idx = c0 + lr; if (idx > re-1) idx = re-1;
      short8 af = (short8)0;
      if (kb < 3){
        ushort8 t = *reinterpret_cast<const ushort8*>(eap24 + (size_t)idx*24 + kb*8);
        af = *reinterpret_cast<short8*>(&t);
      }
      if (lr >= cnt) af = (short8)0;
      return af;
    };
    const int GS = gridDim.x - GG;
    int wid = (blockIdx.x - GG)*4 + (tid>>6);
    const int NW = GS*4;
    for (int nA = wid; nA < NNODES; nA += 2*NW){
      int nB = nA + NW;
      bool hasB = (nB < NNODES);
      int rsA = rowptr[nA], reA = rowptr[nA+1];
      int rsB = 0, reB = 0;
      if (hasB){ rsB = rowptr[nB]; reB = rowptr[nB+1]; }
      float sA[8], sB[8];
      #pragma unroll
      for (int nf=0;nf<8;++nf){ sA[nf]=0.f; sB[nf]=0.f; }
      int cA = rsA, cB = rsB;
      while (cA < reA || cB < reB){
        bool dA = cA < reA, dB = cB < reB;
        short8 afA = (short8)0, afB = (short8)0;
        if (dA) afA = loadC(cA, reA);
        if (dB) afB = loadC(cB, reB);
        if (dA){
          #pragma unroll
          for (int nf=0;nf<8;++nf){
            f32x4 acc = (f32x4)0.f;
            acc = __builtin_amdgcn_mfma_f32_16x16x32_bf16(afA, bh[nf], acc, 0,0,0);
            #pragma unroll
            for (int j=0;j<4;++j){
              float v = acc[j];                  // leaky(v) = 0.55v + 0.45|v|
              sA[nf] = fmaf(0.55f, v, sA[nf]);
              sA[nf] = fmaf(0.45f, fabsf(v), sA[nf]);
            }
          }
        }
        if (dB){
          #pragma unroll
          for (int nf=0;nf<8;++nf){
            f32x4 acc = (f32x4)0.f;
            acc = __builtin_amdgcn_mfma_f32_16x16x32_bf16(afB, bh[nf], acc, 0,0,0);
            #pragma unroll
            for (int j=0;j<4;++j){
              float v = acc[j];
              sB[nf] = fmaf(0.55f, v, sB[nf]);
              sB[nf] = fmaf(0.45f, fabsf(v), sB[nf]);
            }
          }
        }
        cA += 16; cB += 16;
      }
      {
        #pragma unroll
        for (int nf=0;nf<8;++nf){
          float v = sA[nf];
          v += __shfl_xor(v, 16);
          v += __shfl_xor(v, 32);
          sA[nf] = v;
        }
        float va = sA[0], vb = sA[1];
        if (kb == 1){ va = sA[2]; vb = sA[3]; }
        if (kb == 2){ va = sA[4]; vb = sA[5]; }
        if (kb == 3){ va = sA[6]; vb = sA[7]; }
        s1h[(size_t)nA*EMBD + kb*32 + lr]      = f2h(va);
        s1h[(size_t)nA*EMBD + kb*32 + 16 + lr] = f2h(vb);
      }
      if (hasB){
        #pragma unroll
        for (int nf=0;nf<8;++nf){
          float v = sB[nf];
          v += __shfl_xor(v, 16);
          v += __shfl_xor(v, 32);
          sB[nf] = v;
        }
        float va = sB[0], vb = sB[1];
        if (kb == 1){ va = sB[2]; vb = sB[3]; }
        if (kb == 2){ va = sB[4]; vb = sB[5]; }
        if (kb == 3){ va = sB[6]; vb = sB[7]; }
        s1h[(size_t)nB*EMBD + kb*32 + lr]      = f2h(va);
        s1h[(size_t)nB*EMBD + kb*32 + 16 + lr] = f2h(vb);
      }
    }
  }
}

// ------------- tier-B combined edge dispatch (round-8/9 path, fp32 outputs) -------------
__global__ __launch_bounds__(256) void k_edge2(
    const unsigned short* __restrict__ hh, const int* __restrict__ rowptr,
    const int* __restrict__ srcp, const unsigned short* __restrict__ eap24,
    const float* __restrict__ ew1l, const float* __restrict__ eb1l,
    const float* __restrict__ eb2l, const float* __restrict__ selfel,
    float* __restrict__ S1, float* __restrict__ base, int GG)
{
  int tid = threadIdx.x;
  if ((int)blockIdx.x < GG){
    int li = tid & 31;
    int c4 = li*4;
    float4 sf4 = *(const float4*)(selfel + c4);
    float4 e24 = *(const float4*)(eb2l + c4);
    int slot = blockIdx.x*8 + (tid>>5);
    const int NS = GG*8;
    for (int node = slot; node < NNODES; node += NS){
      int rs = rowptr[node], re = rowptr[node+1];
      f32x4 b = (f32x4)0.f;
      for (int c0 = rs; c0 < re; c0 += 8){
        int cnt = re - c0;
        #pragma unroll
        for (int p=0;p<8;++p){
          int e = c0 + p; if (e > re-1) e = re-1;
          float m = (p < cnt) ? 1.f : 0.f;
          int sp = srcp[e];
          uint2 hv = *(const uint2*)(hh + (size_t)sp*EMBD + c4);
          b[0] = fmaf(m, h2f((unsigned short)(hv.x & 0xffffu)), b[0]);
          b[1] = fmaf(m, h2f((unsigned short)(hv.x >> 16)),     b[1]);
          b[2] = fmaf(m, h2f((unsigned short)(hv.y & 0xffffu)), b[2]);
          b[3] = fmaf(m, h2f((unsigned short)(hv.y >> 16)),     b[3]);
        }
      }
      float deg = (float)(re - rs);
      uint2 hn = *(const uint2*)(hh + (size_t)node*EMBD + c4);
      float4 o;
      o.x = b[0] + h2f((unsigned short)(hn.x & 0xffffu)) + sf4.x + deg*e24.x;
      o.y = b[1] + h2f((unsigned short)(hn.x >> 16))     + sf4.y + deg*e24.y;
      o.z = b[2] + h2f((unsigned short)(hn.y & 0xffffu)) + sf4.z + deg*e24.z;
      o.w = b[3] + h2f((unsigned short)(hn.y >> 16))     + sf4.w + deg*e24.w;
      *(float4*)(base + (size_t)node*EMBD + c4) = o;
    }
  } else {
    int lane = tid & 63;
    int lr = lane & 15, kb = lane >> 4;
    short8 bh[8];
    #pragma unroll
    for (int nf=0; nf<8; ++nf){
      int col = nf*16 + lr;
      ushort8 hh8;
      #pragma unroll
      for (int j=0;j<8;++j){
        int k = kb*8 + j;
        float v = 0.f;
        if (k < EDIM) v = ew1l[k*EMBD + col];
        else if (k == EDIM) v = eb1l[col];
        hh8[j] = f2b(v);
      }
      bh[nf] = *reinterpret_cast<short8*>(&hh8);
    }
    auto loadC = [&](int c0, int re)->short8{
      int cnt = re - c0;
      int idx = c0 + lr; if (idx > re-1) idx = re-1;
      short8 af = (short8)0;
      if (kb < 3){
        ushort8 t = *reinterpret_cast<const ushort8*>(eap24 + (size_t)idx*24 + kb*8);
        af = *reinterpret_cast<short8*>(&t);
      }
      if (lr >= cnt) af = (short8)0;
      return af;
    };
    const int GS = gridDim.x - GG;
    int wid = (blockIdx.x - GG)*4 + (tid>>6);
    const int NW = GS*4;
    for (int nA = wid; nA < NNODES; nA += 2*NW){
      int nB = nA + NW;
      bool hasB = (nB < NNODES);
      int rsA = rowptr[nA], reA = rowptr[nA+1];
      int rsB = 0, reB = 0;
      if (hasB){ rsB = rowptr[nB]; reB = rowptr[nB+1]; }
      float sA[8], sB[8];
      #pragma unroll
      for (int nf=0;nf<8;++nf){ sA[nf]=0.f; sB[nf]=0.f; }
      int cA = rsA, cB = rsB;
      while (cA < reA || cB < reB){
        bool dA = cA < reA, dB = cB < reB;
        short8 afA = (short8)0, afB = (short8)0;
        if (dA) afA = loadC(cA, reA);
        if (dB) afB = loadC(cB, reB);
        if (dA){
          #pragma unroll
          for (int nf=0;nf<8;++nf){
            f32x4 acc = (f32x4)0.f;
            acc = __builtin_amdgcn_mfma_f32_16x16x32_bf16(afA, bh[nf], acc, 0,0,0);
            #pragma unroll
            for (int j=0;j<4;++j){
              float v = acc[j];
              sA[nf] = fmaf(0.55f, v, sA[nf]);
              sA[nf] = fmaf(0.45f, fabsf(v), sA[nf]);
            }
          }
        }
        if (dB){
          #pragma unroll
          for (int nf=0;nf<8;++nf){
            f32x4 acc = (f32x4)0.f;
            acc = __builtin_amdgcn_mfma_f32_16x16x32_bf16(afB, bh[nf], acc, 0,0,0);
            #pragma unroll
            for (int j=0;j<4;++j){
              float v = acc[j];
              sB[nf] = fmaf(0.55f, v, sB[nf]);
              sB[nf] = fmaf(0.45f, fabsf(v), sB[nf]);
            }
          }
        }
        cA += 16; cB += 16;
      }
      {
        #pragma unroll
        for (int nf=0;nf<8;++nf){
          float v = sA[nf];
          v += __shfl_xor(v, 16);
          v += __shfl_xor(v, 32);
          sA[nf] = v;
        }
        float va = sA[0], vb = sA[1];
        if (kb == 1){ va = sA[2]; vb = sA[3]; }
        if (kb == 2){ va = sA[4]; vb = sA[5]; }
        if (kb == 3){ va = sA[6]; vb = sA[7]; }
        S1[(size_t)nA*EMBD + kb*32 + lr]      = va;
        S1[(size_t)nA*EMBD + kb*32 + 16 + lr] = vb;
      }
      if (hasB){
        #pragma unroll
        for (int nf=0;nf<8;++nf){
          float v = sB[nf];
          v += __shfl_xor(v, 16);
          v += __shfl_xor(v, 32);
          sB[nf] = v;
        }
        float va = sB[0], vb = sB[1];
        if (kb == 1){ va = sB[2]; vb = sB[3]; }
        if (kb == 2){ va = sB[4]; vb = sB[5]; }
        if (kb == 3){ va = sB[6]; vb = sB[7]; }
        S1[(size_t)nB*EMBD + kb*32 + lr]      = va;
        S1[(size_t)nB*EMBD + kb*32 + 16 + lr] = vb;
      }
    }
  }
}

// ------------- OLD edge kernel (tier-C fallback) -------------
__global__ __launch_bounds__(256) void k_edge(
    const float* __restrict__ h, const int* __restrict__ rowptr,
    const int* __restrict__ perm, const int* __restrict__ srcp,
    const float* __restrict__ edge_attr, const float* __restrict__ eaperm,
    const float* __restrict__ ew1l, const float* __restrict__ eb1l,
    const float* __restrict__ eb2l, const float* __restrict__ selfel,
    float* __restrict__ S1, float* __restrict__ base)
{
  __shared__ float w1s[EDIM*EMBD];
  __shared__ float b1s[EMBD];
  int tid = threadIdx.x;
  for (int i = tid; i < EDIM*EMBD; i += 256) w1s[i] = ew1l[i];
  if (tid < EMBD) b1s[tid] = eb1l[tid];
  __syncthreads();
  int lane = tid & 63;
  int node = blockIdx.x*4 + (tid >> 6);
  if (node >= NNODES) return;
  int rs = rowptr[node], re = rowptr[node+1];
  int c0 = lane*2;
  float s1x=0.f, s1y=0.f, bx=0.f, by=0.f;
  for (int i = rs; i < re; ++i){
    int s = __builtin_amdgcn_readfirstlane(srcp[i]);
    const float* ea;
    if (eaperm){
      ea = eaperm + (size_t)__builtin_amdgcn_readfirstlane(i)*EDIM;
    } else {
      ea = edge_attr + (size_t)__builtin_amdgcn_readfirstlane(perm[i])*EDIM;
    }
    float2 hs = *(const float2*)(h + (size_t)s*EMBD + c0);
    bx += hs.x; by += hs.y;
    float d0 = b1s[c0], d1 = b1s[c0+1];
    #pragma unroll
    for (int k=0;k<EDIM;++k){
      float av = ea[k];
      d0 += av * w1s[k*EMBD + c0];
      d1 += av * w1s[k*EMBD + c0 + 1];
    }
    s1x += leakyf(d0); s1y += leakyf(d1);
  }
  float deg = (float)(re - rs);
  float2 hv = *(const float2*)(h + (size_t)node*EMBD + c0);
  *(float2*)(S1 + (size_t)node*EMBD + c0) = make_float2(s1x, s1y);
  float bvx = bx + hv.x + selfel[c0]   + deg*eb2l[c0];
  float bvy = by + hv.y + selfel[c0+1] + deg*eb2l[c0+1];
  *(float2*)(base + (size_t)node*EMBD + c0) = make_float2(bvx, bvy);
}

// ------------- MFMA GEMM: C = act(A[M,K] @ B + bias), split-bf16 precision -------------
// A sources: fp32 (Af/A1, CONCAT), bf16 (Ab), or fp16 (Afh; with CONCAT: Afh first half, Afh2 second).
template<int BN, int WGM, int WGN, bool ALO, bool BLO, int ACT, bool STATS, bool OBF16,
         bool CONCAT, bool KCHK, bool ABF16, bool AH16>
__global__ __launch_bounds__(512) void k_mgemm(
    const float* __restrict__ Af, const float* __restrict__ A1,
    const __hip_bfloat16* __restrict__ Ab,
    const unsigned short* __restrict__ Afh, const unsigned short* __restrict__ Afh2,
    int M, int Kreal, int Kpad, int lda,
    const __hip_bfloat16* __restrict__ Bp,
    const float* __restrict__ bias,
    float* __restrict__ Cf, __hip_bfloat16* __restrict__ Cb, int ldc,
    float* __restrict__ stats, unsigned short* __restrict__ Ch)
{
  static_assert(WGM*WGN == 8, "8 waves");
  constexpr int BM = 128;
  constexpr int MF = BM/(16*WGM);
  constexpr int NF = BN/(16*WGN);
  constexpr int LDS_ROW = 40;
  __shared__ __align__(16) unsigned short Ah[BM*LDS_ROW];
  __shared__ __align__(16) unsigned short Al[ALO ? BM*LDS_ROW : 8];
  __shared__ float ssum[STATS ? BN : 4];
  __shared__ float ssq [STATS ? BN : 4];

  int tid = threadIdx.x;
  int row0 = blockIdx.x*BM;
  int w = tid >> 6, lane = tid & 63;
  int wm = w / WGN, wn = w % WGN;
  int lr = lane & 15, kb = lane >> 4;
  int wrow = wm*MF*16, wcol = wn*NF*16;

  if (STATS && tid < BN){ ssum[tid] = 0.f; ssq[tid] = 0.f; }

  f32x4 acc[MF][NF];
  #pragma unroll
  for (int a=0;a<MF;++a)
    #pragma unroll
    for (int b=0;b<NF;++b) acc[a][b] = (f32x4)0.f;

  const size_t planeSz = (size_t)Kpad*BN;
  int sr = tid >> 2;
  int skq = (tid & 3)*8;
  int grow = row0 + sr;
  const int KS = Kpad >> 5;

  for (int ks = 0; ks < KS; ++ks){
    int k0 = ks << 5;
    int kg = k0 + skq;
    ushort8 hv, lv;
    if (ABF16){
      short8 raw = (short8)0;
      if (grow < M) raw = *reinterpret_cast<const short8*>((const unsigned short*)Ab + (size_t)grow*lda + kg);
      hv = *reinterpret_cast<ushort8*>(&raw);
    } else {
      float v[8];
      if (AH16){
        const unsigned short* s16;
        if (CONCAT) s16 = (kg < EMBD) ? (Afh + (size_t)grow*EMBD + kg)
                                      : (Afh2 + (size_t)grow*EMBD + (kg - EMBD));
        else        s16 = Afh + (size_t)grow*lda + kg;
        ushort8 raw = (ushort8)0;
        if (grow < M) raw = *reinterpret_cast<const ushort8*>(s16);
        #pragma unroll
        for (int i=0;i<8;++i) v[i] = h2f(raw[i]);
      } else if (KCHK){
        #pragma unroll
        for (int i=0;i<8;++i)
          v[i] = (grow < M && kg+i < Kreal) ? Af[(size_t)grow*lda + kg + i] : 0.f;
      } else {
        const float* s;
        if (CONCAT) s = (kg < EMBD) ? (Af + (size_t)grow*lda + kg) : (A1 + (size_t)grow*lda + (kg - EMBD));
        else        s = Af + (size_t)grow*lda + kg;
        float4 p0 = make_float4(0,0,0,0), p1 = make_float4(0,0,0,0);
        if (grow < M){ p0 = *(const float4*)s; p1 = *(const float4*)(s+4); }
        v[0]=p0.x; v[1]=p0.y; v[2]=p0.z; v[3]=p0.w;
        v[4]=p1.x; v[5]=p1.y; v[6]=p1.z; v[7]=p1.w;
      }
      #pragma unroll
      for (int i=0;i<8;++i){
        unsigned short h16 = f2b(v[i]);
        hv[i] = h16;
        if (ALO) lv[i] = f2b(v[i] - b2f(h16));
      }
    }
    __syncthreads();
    *reinterpret_cast<ushort8*>(&Ah[sr*LDS_ROW + skq]) = hv;
    if (ALO && !ABF16) *reinterpret_cast<ushort8*>(&Al[sr*LDS_ROW + skq]) = lv;
    __syncthreads();

    short8 ah[MF], al[MF];
    #pragma unroll
    for (int mf=0; mf<MF; ++mf){
      int r = (wrow + mf*16 + lr)*LDS_ROW + kb*8;
      ah[mf] = *reinterpret_cast<const short8*>(&Ah[r]);
      if (ALO) al[mf] = *reinterpret_cast<const short8*>(&Al[r]);
    }
    const unsigned short* bb = (const unsigned short*)Bp + (size_t)ks*BN*32;
    short8 bh[NF], blv[NF];
    #pragma unroll
    for (int nf=0; nf<NF; ++nf){
      size_t off = (size_t)(wcol + nf*16 + lr)*32 + kb*8;
      bh[nf] = *reinterpret_cast<const short8*>(bb + off);
      if (BLO) blv[nf] = *reinterpret_cast<const short8*>(bb + planeSz + off);
    }
    #pragma unroll
    for (int mf=0; mf<MF; ++mf){
      #pragma unroll
      for (int nf=0; nf<NF; ++nf){
        acc[mf][nf] = __builtin_amdgcn_mfma_f32_16x16x32_bf16(ah[mf], bh[nf], acc[mf][nf], 0, 0, 0);
        if (BLO)
          acc[mf][nf] = __builtin_amdgcn_mfma_f32_16x16x32_bf16(ah[mf], blv[nf], acc[mf][nf], 0, 0, 0);
        if (ALO)
          acc[mf][nf] = __builtin_amdgcn_mfma_f32_16x16x32_bf16(al[mf], bh[nf], acc[mf][nf], 0, 0, 0);
      }
    }
  }

  float bcol[NF];
  #pragma unroll
  for (int nf=0; nf<NF; ++nf) bcol[nf] = bias ? bias[wcol + nf*16 + lr] : 0.f;
  float s[NF], sq[NF];
  #pragma unroll
  for (int nf=0; nf<NF; ++nf){ s[nf]=0.f; sq[nf]=0.f; }

  #pragma unroll
  for (int mf=0; mf<MF; ++mf){
    #pragma unroll
    for (int j=0; j<4; ++j){
      int r = row0 + wrow + mf*16 + kb*4 + j;
      if (r < M){
        #pragma unroll
        for (int nf=0; nf<NF; ++nf){
          int c = wcol + nf*16 + lr;
          float v = acc[mf][nf][j] + bcol[nf];
          if (ACT == 1) v = leakyf(v);
          if (ACT == 2) v = fmaxf(v, 0.f);
          if (OBF16) Cb[(size_t)r*ldc + c] = __float2bfloat16(v);
          else if (Cf) Cf[(size_t)r*ldc + c] = v;
          if (Ch) Ch[(size_t)r*ldc + c] = f2h(v);
          if (STATS){ s[nf] += v; sq[nf] += v*v; }
        }
      }
    }
  }
  if (STATS){
    #pragma unroll
    for (int nf=0; nf<NF; ++nf){
      atomicAdd(&ssum[wcol + nf*16 + lr], s[nf]);
      atomicAdd(&ssq [wcol + nf*16 + lr], sq[nf]);
    }
    __syncthreads();
    if (tid < BN){
      atomicAdd(&stats[tid], ssum[tid]);
      atomicAdd(&stats[BN + tid], ssq[tid]);
    }
  }
}

// ------------- BatchNorm normalize (+optional relu; fp32 and/or fp16 outputs) -------------
__global__ __launch_bounds__(256) void k_bn(const float* __restrict__ hh, const float* __restrict__ stats,
                                            const float* __restrict__ gamma, const float* __restrict__ beta,
                                            float* __restrict__ out, unsigned short* __restrict__ outh,
                                            int dorelu){
  int idx = blockIdx.x*256 + threadIdx.x;
  if (idx >= NNODES*(EMBD/4)) return;
  int c0 = (idx & (EMBD/4 - 1)) * 4;
  float4 v = *(const float4*)(hh + (size_t)idx*4);
  float o[4] = {v.x, v.y, v.z, v.w};
  const float invN = 1.f / (float)NNODES;
  #pragma unroll
  for (int i=0;i<4;++i){
    int c = c0 + i;
    float mean = stats[c] * invN;
    float var  = stats[EMBD + c] * invN - mean*mean;
    float inv  = rsqrtf(fmaxf(var, 0.f) + BNEPS);
    float y = (o[i] - mean) * inv * gamma[c] + beta[c];
    if (dorelu) y = fmaxf(y, 0.f);
    o[i] = y;
  }
  if (out) *(float4*)(out + (size_t)idx*4) = make_float4(o[0],o[1],o[2],o[3]);
  if (outh){
    uint2 pk;
    pk.x = (unsigned)f2h(o[0]) | ((unsigned)f2h(o[1]) << 16);
    pk.y = (unsigned)f2h(o[2]) | ((unsigned)f2h(o[3]) << 16);
    *reinterpret_cast<uint2*>(outh + (size_t)idx*4) = pk;
  }
}

// ---------------- launcher ----------------
extern "C" void kernel_launch(void* const* d_in, const int* in_sizes, int n_in,
                              void* d_out, int out_size, void* d_ws, size_t ws_size,
                              hipStream_t stream)
{
  const float* x   = (const float*)d_in[0];
  const float* ea  = (const float*)d_in[1];
  const float* iw1 = (const float*)d_in[2];
  const float* ib1 = (const float*)d_in[3];
  const float* iw2 = (const float*)d_in[4];
  const float* ib2 = (const float*)d_in[5];
  const float* ew1 = (const float*)d_in[6];
  const float* eb1 = (const float*)d_in[7];
  const float* ew2 = (const float*)d_in[8];
  const float* eb2 = (const float*)d_in[9];
  const float* mw1 = (const float*)d_in[10];
  const float* mb1 = (const float*)d_in[11];
  const float* mw2 = (const float*)d_in[12];
  const float* mb2 = (const float*)d_in[13];
  const float* gamma = (const float*)d_in[14];
  const float* beta  = (const float*)d_in[15];
  const int* eidx = (const int*)d_in[16];
  const int* srcI = eidx;
  const int* dstI = eidx + NEDGES;

  char* p = (char*)d_ws;
  auto alloc = [&](size_t bytes)->char*{
    char* r = p; p += (bytes + 255) & ~(size_t)255; return r;
  };
  float* S1    = (float*)alloc((size_t)NNODES*EMBD*4);
  float* base  = (float*)alloc((size_t)NNODES*EMBD*4);
  __hip_bfloat16* tbuf = (__hip_bfloat16*)alloc((size_t)NNODES*2*EMBD*2);
  int* perm   = (int*)alloc((size_t)NEDGES*4);     // == einv in new path
  int* srcp   = (int*)alloc((size_t)NEDGES*4);
  int* rowptr = (int*)alloc((size_t)(NNODES+1)*4);
  int* cursor = (int*)alloc((size_t)NNODES*4);
  int* bsum   = (int*)alloc(4096);
  int* boff   = (int*)alloc(4096);
  float* selfe = (float*)alloc(NLAYER*EMBD*4);
  float* stats = (float*)alloc(2*EMBD*4);
  float* wc    = (float*)alloc((size_t)NLAYER*EMBD*2*EMBD*4);
  __hip_bfloat16* Bi1 = (__hip_bfloat16*)alloc((size_t)192*EMBD*2*2);
  __hip_bfloat16* Bi2 = (__hip_bfloat16*)alloc((size_t)EMBD*EMBD*2*2);
  __hip_bfloat16* B1  = (__hip_bfloat16*)alloc((size_t)NLAYER*256*256*2*2);
  __hip_bfloat16* B2  = (__hip_bfloat16*)alloc((size_t)NLAYER*256*EMBD*2*2);
  size_t used = (size_t)(p - (char*)d_ws);

  const size_t szEap  = (size_t)NEDGES*24*2;
  const size_t szHh   = (size_t)NNODES*EMBD*2;
  const size_t szH16  = (size_t)NNODES*EMBD*2;
  const size_t szHbuf = (size_t)NNODES*EMBD*4;

  bool tierN = (ws_size >= used + szEap + szHh + 2*szH16 + 1024);   // fp16 S1/base path
  bool tierB = !tierN && (ws_size >= used + szEap + szHh + 512);
  unsigned short* eap24 = nullptr;
  unsigned short* hh16 = nullptr;
  unsigned short* s1h = nullptr;
  unsigned short* baseh = nullptr;
  float* hbuf = nullptr;
  float* eaperm = nullptr;
  if (tierN){
    eap24 = (unsigned short*)alloc(szEap);
    hh16  = (unsigned short*)alloc(szHh);
    s1h   = (unsigned short*)alloc(szH16);
    baseh = (unsigned short*)alloc(szH16);
  } else if (tierB){
    eap24 = (unsigned short*)alloc(szEap);
    hh16  = (unsigned short*)alloc(szHh);
  } else {
    hbuf = (float*)alloc(szHbuf);
    used = (size_t)(p - (char*)d_ws);
    if (ws_size >= used + (size_t)NEDGES*EDIM*4 + 256)
      eaperm = (float*)alloc((size_t)NEDGES*EDIM*4);
  }
  bool use_new = tierN || tierB;

  // ---- CSR build ----
  hipMemsetAsync(cursor, 0, (size_t)NNODES*4, stream);
  k_hist<<<(NEDGES+255)/256, 256, 0, stream>>>(dstI, cursor);
  int nb = (NNODES+255)/256;
  k_scan1<<<nb, 256, 0, stream>>>(cursor, rowptr, bsum);
  k_scan2<<<1, 512, 0, stream>>>(bsum, boff, nb);
  k_scan3<<<(NNODES+255)/256, 256, 0, stream>>>(rowptr, boff);
  k_curcopy<<<(NNODES+255)/256, 256, 0, stream>>>(rowptr, cursor);
  if (use_new){
    k_fill_pos<<<(NEDGES+255)/256, 256, 0, stream>>>(dstI, cursor, perm);
    k_fill_ea<<<(NEDGES+255)/256, 256, 0, stream>>>(perm, srcI, ea, srcp, eap24);
  } else {
    k_fill<<<(NEDGES+255)/256, 256, 0, stream>>>(srcI, dstI, ea, cursor, perm, srcp, eaperm);
  }
  k_selfe<<<NLAYER, EMBD, 0, stream>>>(eb1, ew2, eb2, selfe);

  // ---- weight prep ----
  k_wc<<<(NLAYER*EMBD*2*EMBD)/256, 256, 0, stream>>>(ew2, mw1, wc);
  k_pack<<<(192*EMBD+255)/256, 256, 0, stream>>>(iw1, XDIM, iw1, XDIM, 192, EMBD, Bi1);
  k_pack<<<(EMBD*EMBD+255)/256, 256, 0, stream>>>(iw2, EMBD, iw2, EMBD, EMBD, EMBD, Bi2);
  for (int l=0; l<NLAYER; ++l){
    k_pack<<<(256*256+255)/256, 256, 0, stream>>>(
        wc + (size_t)l*EMBD*2*EMBD, EMBD, mw1 + (size_t)l*EMBD*2*EMBD, 256, 256, 256,
        B1 + (size_t)l*256*256*2);
    k_pack<<<(256*EMBD+255)/256, 256, 0, stream>>>(
        mw2 + (size_t)l*2*EMBD*EMBD, 256, mw2, 256, 256, EMBD,
        B2 + (size_t)l*256*EMBD*2);
  }

  const int gx = (NNODES + 127)/128;

  // ---- input MLP ----
  k_mgemm<128,4,2, true,true,1,false,false,false,true ,false,false><<<gx, 512, 0, stream>>>(
      x, nullptr, nullptr, nullptr, nullptr, NNODES, XDIM, 192, XDIM, Bi1, ib1,
      S1, nullptr, EMBD, nullptr, nullptr);
  k_mgemm<128,4,2, true,true,0,false,false,false,false,false,false><<<gx, 512, 0, stream>>>(
      S1, nullptr, nullptr, nullptr, nullptr, NNODES, EMBD, EMBD, EMBD, Bi2, ib2,
      use_new ? nullptr : hbuf, nullptr, EMBD, nullptr, use_new ? hh16 : nullptr);

  for (int l=0; l<NLAYER; ++l){
    hipMemsetAsync(stats, 0, 2*EMBD*4, stream);
    if (tierN){
      k_edge4<<<2048, 256, 0, stream>>>(
          hh16, rowptr, srcp, eap24,
          ew1 + (size_t)l*EDIM*EMBD, eb1 + l*EMBD, eb2 + l*EMBD, selfe + l*EMBD,
          s1h, baseh, 1536);
      // t = relu([s1h|baseh](fp16) @ [Wc;mw1] + mb1) -> bf16 [N,256]  (A split hi+lo)
      k_mgemm<256,2,4, true,true,2,false,true ,true ,false,false,true ><<<gx, 512, 0, stream>>>(
          nullptr, nullptr, nullptr, s1h, baseh, NNODES, 256, 256, EMBD,
          B1 + (size_t)l*256*256*2, mb1 + l*2*EMBD, nullptr, tbuf, 2*EMBD, nullptr, nullptr);
    } else if (tierB){
      k_edge2<<<2048, 256, 0, stream>>>(
          hh16, rowptr, srcp, eap24,
          ew1 + (size_t)l*EDIM*EMBD, eb1 + l*EMBD, eb2 + l*EMBD, selfe + l*EMBD,
          S1, base, 1408);
      k_mgemm<256,2,4, true,true,2,false,true ,true ,false,false,false><<<gx, 512, 0, stream>>>(
          S1, base, nullptr, nullptr, nullptr, NNODES, 256, 256, EMBD,
          B1 + (size_t)l*256*256*2, mb1 + l*2*EMBD, nullptr, tbuf, 2*EMBD, nullptr, nullptr);
    } else {
      k_edge<<<NNODES/4, 256, 0, stream>>>(
          hbuf, rowptr, perm, srcp, ea, eaperm,
          ew1 + (size_t)l*EDIM*EMBD, eb1 + l*EMBD, eb2 + l*EMBD, selfe + l*EMBD,
          S1, base);
      k_mgemm<256,2,4, true,true,2,false,true ,true ,false,false,false><<<gx, 512, 0, stream>>>(
          S1, base, nullptr, nullptr, nullptr, NNODES, 256, 256, EMBD,
          B1 + (size_t)l*256*256*2, mb1 + l*2*EMBD, nullptr, tbuf, 2*EMBD, nullptr, nullptr);
    }
    // hh (into S1) = t @ mw2 + mb2, fused BN stats  (bf16 A, bf16-hi B only)
    k_mgemm<128,4,2, false,false,0,true ,false,false,false,true ,false><<<gx, 512, 0, stream>>>(
        nullptr, nullptr, tbuf, nullptr, nullptr, NNODES, 256, 256, 2*EMBD,
        B2 + (size_t)l*256*EMBD*2, mb2 + l*EMBD, S1, nullptr, EMBD, stats, nullptr);
    // BN normalize: intermediate layers -> fp16 h only; last layer -> fp32 d_out
    float* outp; unsigned short* outh;
    if (l == NLAYER-1){ outp = (float*)d_out; outh = nullptr; }
    else if (use_new) { outp = nullptr;       outh = hh16;    }
    else              { outp = hbuf;          outh = nullptr; }
    k_bn<<<(NNODES*(EMBD/4)+255)/256, 256, 0, stream>>>(
        S1, stats, gamma + l*EMBD, beta + l*EMBD, outp, outh, (l < NLAYER-1) ? 1 : 0);
  }
}

// Round 17
// 1834.578 us; speedup vs baseline: 1.1075x; 1.0351x over previous
//
#include <hip/hip_runtime.h>
#include <hip/hip_bf16.h>
#include <hip/hip_fp16.h>
#include <cstdint>
#include <cstddef>

#define NNODES 100000
#define NEDGES 1600000
#define EMBD 128
#define NLAYER 5
#define XDIM 178
#define EDIM 18
#define BNEPS 1e-5f

typedef __attribute__((ext_vector_type(8))) short short8;
typedef __attribute__((ext_vector_type(8))) unsigned short ushort8;
typedef __attribute__((ext_vector_type(4))) float f32x4;

static __device__ __forceinline__ float leakyf(float v){ return v > 0.f ? v : 0.1f*v; }
static __device__ __forceinline__ unsigned short f2b(float v){
  __hip_bfloat16 b = __float2bfloat16(v);
  return *reinterpret_cast<unsigned short*>(&b);
}
static __device__ __forceinline__ float b2f(unsigned short u){
  __hip_bfloat16 b = *reinterpret_cast<__hip_bfloat16*>(&u);
  return __bfloat162float(b);
}
static __device__ __forceinline__ unsigned short f2h(float v){
  __half h = __float2half(v);
  return *reinterpret_cast<unsigned short*>(&h);
}
static __device__ __forceinline__ float h2f(unsigned short u){
  __half h = *reinterpret_cast<__half*>(&u);
  return __half2float(h);
}

// ---------------- CSR build ----------------
__global__ __launch_bounds__(256) void k_hist(const int* __restrict__ dst, int* __restrict__ cnt){
  int e = blockIdx.x*256 + threadIdx.x;
  if (e < NEDGES) atomicAdd(&cnt[dst[e]], 1);
}

__global__ __launch_bounds__(256) void k_scan1(const int* __restrict__ cnt, int* __restrict__ rowptr,
                                               int* __restrict__ bsum){
  __shared__ int s[256];
  int t = threadIdx.x, i = blockIdx.x*256 + t;
  int v = (i < NNODES) ? cnt[i] : 0;
  s[t] = v; __syncthreads();
  for (int off=1; off<256; off<<=1){
    int x = (t>=off) ? s[t-off] : 0; __syncthreads();
    s[t] += x; __syncthreads();
  }
  if (i < NNODES) rowptr[i+1] = s[t];
  if (t == 255) bsum[blockIdx.x] = s[t];
}

__global__ __launch_bounds__(512) void k_scan2(const int* __restrict__ bsum, int* __restrict__ boff, int nb){
  __shared__ int s[512];
  int t = threadIdx.x;
  int v = (t < nb) ? bsum[t] : 0;
  s[t] = v; __syncthreads();
  for (int off=1; off<512; off<<=1){
    int x = (t>=off) ? s[t-off] : 0; __syncthreads();
    s[t] += x; __syncthreads();
  }
  if (t < nb) boff[t] = s[t] - v;
}

__global__ __launch_bounds__(256) void k_scan3(int* __restrict__ rowptr, const int* __restrict__ boff){
  int i = blockIdx.x*256 + threadIdx.x;
  if (i < NNODES) rowptr[i+1] += boff[i>>8];
  if (i == 0) rowptr[0] = 0;
}

__global__ __launch_bounds__(256) void k_curcopy(const int* __restrict__ rowptr, int* __restrict__ cursor){
  int i = blockIdx.x*256 + threadIdx.x;
  if (i < NNODES) cursor[i] = rowptr[i];
}

// pass A: position + inverse permutation only (4B scatter into L2-resident 6.4MB array)
__global__ __launch_bounds__(256) void k_fill_pos(const int* __restrict__ dst, int* __restrict__ cursor,
                                                  int* __restrict__ einv){
  int e = blockIdx.x*256 + threadIdx.x;
  if (e >= NEDGES) return;
  int pos = atomicAdd(&cursor[dst[e]], 1);
  einv[pos] = e;
}

// pass B: pos-coalesced; random READS of ea rows; coalesced writes of eap24+srcp
__global__ __launch_bounds__(256) void k_fill_ea(const int* __restrict__ einv, const int* __restrict__ src,
                                                 const float* __restrict__ ea,
                                                 int* __restrict__ srcp, unsigned short* __restrict__ eap24){
  int pos = blockIdx.x*256 + threadIdx.x;
  if (pos >= NEDGES) return;
  int e = einv[pos];
  srcp[pos] = src[e];
  const float* a = ea + (size_t)e*EDIM;
  float v[18];
  #pragma unroll
  for (int k=0;k<9;++k){
    float2 t = *(const float2*)(a + 2*k);
    v[2*k] = t.x; v[2*k+1] = t.y;
  }
  ushort8 r0, r1, r2;
  #pragma unroll
  for (int k=0;k<8;++k) r0[k] = f2b(v[k]);
  #pragma unroll
  for (int k=0;k<8;++k) r1[k] = f2b(v[8+k]);
  #pragma unroll
  for (int k=0;k<8;++k) r2[k] = 0;
  r2[0] = f2b(v[16]); r2[1] = f2b(v[17]);
  r2[2] = 0x3F80;   // bf16 1.0 at k=18 -> bias slot
  unsigned short* o = eap24 + (size_t)pos*24;
  *reinterpret_cast<ushort8*>(o)      = r0;
  *reinterpret_cast<ushort8*>(o + 8)  = r1;
  *reinterpret_cast<ushort8*>(o + 16) = r2;
}

// old-path fill (fallback)
__global__ __launch_bounds__(256) void k_fill(const int* __restrict__ src, const int* __restrict__ dst,
                                              const float* __restrict__ ea, int* __restrict__ cursor,
                                              int* __restrict__ perm, int* __restrict__ srcp,
                                              float* __restrict__ eap){
  int e = blockIdx.x*256 + threadIdx.x;
  if (e >= NEDGES) return;
  int pos = atomicAdd(&cursor[dst[e]], 1);
  perm[pos] = e;
  srcp[pos] = src[e];
  if (eap){
    const float* a = ea + (size_t)e*EDIM;
    float* o = eap + (size_t)pos*EDIM;
    #pragma unroll
    for (int k=0;k<EDIM;++k) o[k] = a[k];
  }
}

// self_e[l] = leaky(eb1[l]) @ ew2[l] + eb2[l]
__global__ __launch_bounds__(128) void k_selfe(const float* __restrict__ eb1, const float* __restrict__ ew2,
                                               const float* __restrict__ eb2, float* __restrict__ selfe){
  int l = blockIdx.x, c = threadIdx.x;
  const float* b1 = eb1 + l*EMBD;
  const float* w2 = ew2 + (size_t)l*EMBD*EMBD;
  float acc = eb2[l*EMBD + c];
  for (int j=0;j<EMBD;++j) acc += leakyf(b1[j]) * w2[j*EMBD + c];
  selfe[l*EMBD + c] = acc;
}

// Wc[l] = ew2[l] @ mw1[l]  ([128][256] fp32)
__global__ __launch_bounds__(256) void k_wc(const float* __restrict__ ew2, const float* __restrict__ mw1,
                                            float* __restrict__ wc){
  int idx = blockIdx.x*256 + threadIdx.x;       // 5*128*256
  int l = idx >> 15, rem = idx & 32767;
  int i = rem >> 8, n = rem & 255;
  const float* e = ew2 + (size_t)l*EMBD*EMBD + i*EMBD;
  const float* m = mw1 + (size_t)l*EMBD*2*EMBD + n;
  float acc = 0.f;
  #pragma unroll 4
  for (int j=0;j<EMBD;++j) acc += e[j]*m[(size_t)j*2*EMBD];
  wc[idx] = acc;
}

// pack B [Kpad x N] into hi/lo bf16 planes laid out [ks][n][kk]
__global__ __launch_bounds__(256) void k_pack(const float* __restrict__ s1, int rows1,
                                              const float* __restrict__ s2, int Kreal,
                                              int Kpad, int N, __hip_bfloat16* __restrict__ out){
  int idx = blockIdx.x*256 + threadIdx.x;
  if (idx >= Kpad*N) return;
  int k = idx / N, n = idx - k*N;
  float v = 0.f;
  if (k < rows1) v = s1[(size_t)k*N + n];
  else if (k < Kreal) v = s2[(size_t)(k-rows1)*N + n];
  unsigned short hi = f2b(v);
  unsigned short lo = f2b(v - b2f(hi));
  size_t o = (size_t)(k>>5)*N*32 + (size_t)n*32 + (k&31);
  unsigned short* po = (unsigned short*)out;
  po[o] = hi;
  po[(size_t)Kpad*N + o] = lo;
}

// ------------- tier-N combined edge dispatch: 2-node-interleaved gather + S1 MFMA, fp16 outputs -------------
__global__ __launch_bounds__(256) void k_edge4(
    const unsigned short* __restrict__ hh, const int* __restrict__ rowptr,
    const int* __restrict__ srcp, const unsigned short* __restrict__ eap24,
    const float* __restrict__ ew1l, const float* __restrict__ eb1l,
    const float* __restrict__ eb2l, const float* __restrict__ selfel,
    unsigned short* __restrict__ s1h, unsigned short* __restrict__ baseh, int GG)
{
  int tid = threadIdx.x;
  if ((int)blockIdx.x < GG){
    // ---------- gather path: half-wave per node, 2-node interleave (16 loads in flight) ----------
    int li = tid & 31;
    int c4 = li*4;
    float4 sf4 = *(const float4*)(selfel + c4);
    float4 e24 = *(const float4*)(eb2l + c4);
    int slot = blockIdx.x*8 + (tid>>5);
    const int NS = GG*8;
    for (int nA = slot; nA < NNODES; nA += 2*NS){
      int nB = nA + NS;
      bool hasB = (nB < NNODES);
      int rsA = rowptr[nA], reA = rowptr[nA+1];
      int rsB = 0, reB = 0;
      if (hasB){ rsB = rowptr[nB]; reB = rowptr[nB+1]; }
      f32x4 bA = (f32x4)0.f, bB = (f32x4)0.f;
      int cA = rsA, cB = rsB;
      while (cA < reA || cB < reB){
        bool dA = cA < reA, dB = cB < reB;
        uint2 hvA[8], hvB[8];
        float mA[8], mB[8];
        if (dA){
          #pragma unroll
          for (int p=0;p<8;++p){
            int e = cA + p; if (e > reA-1) e = reA-1;
            mA[p] = (cA + p < reA) ? 1.f : 0.f;
            int sp = srcp[e];
            hvA[p] = *(const uint2*)(hh + (size_t)sp*EMBD + c4);
          }
        }
        if (dB){
          #pragma unroll
          for (int p=0;p<8;++p){
            int e = cB + p; if (e > reB-1) e = reB-1;
            mB[p] = (cB + p < reB) ? 1.f : 0.f;
            int sp = srcp[e];
            hvB[p] = *(const uint2*)(hh + (size_t)sp*EMBD + c4);
          }
        }
        if (dA){
          #pragma unroll
          for (int p=0;p<8;++p){
            bA[0] = fmaf(mA[p], h2f((unsigned short)(hvA[p].x & 0xffffu)), bA[0]);
            bA[1] = fmaf(mA[p], h2f((unsigned short)(hvA[p].x >> 16)),     bA[1]);
            bA[2] = fmaf(mA[p], h2f((unsigned short)(hvA[p].y & 0xffffu)), bA[2]);
            bA[3] = fmaf(mA[p], h2f((unsigned short)(hvA[p].y >> 16)),     bA[3]);
          }
        }
        if (dB){
          #pragma unroll
          for (int p=0;p<8;++p){
            bB[0] = fmaf(mB[p], h2f((unsigned short)(hvB[p].x & 0xffffu)), bB[0]);
            bB[1] = fmaf(mB[p], h2f((unsigned short)(hvB[p].x >> 16)),     bB[1]);
            bB[2] = fmaf(mB[p], h2f((unsigned short)(hvB[p].y & 0xffffu)), bB[2]);
            bB[3] = fmaf(mB[p], h2f((unsigned short)(hvB[p].y >> 16)),     bB[3]);
          }
        }
        cA += 8; cB += 8;
      }
      {
        float deg = (float)(reA - rsA);
        uint2 hn = *(const uint2*)(hh + (size_t)nA*EMBD + c4);
        float ox = bA[0] + h2f((unsigned short)(hn.x & 0xffffu)) + sf4.x + deg*e24.x;
        float oy = bA[1] + h2f((unsigned short)(hn.x >> 16))     + sf4.y + deg*e24.y;
        float oz = bA[2] + h2f((unsigned short)(hn.y & 0xffffu)) + sf4.z + deg*e24.z;
        float ow = bA[3] + h2f((unsigned short)(hn.y >> 16))     + sf4.w + deg*e24.w;
        uint2 pk;
        pk.x = (unsigned)f2h(ox) | ((unsigned)f2h(oy) << 16);
        pk.y = (unsigned)f2h(oz) | ((unsigned)f2h(ow) << 16);
        *reinterpret_cast<uint2*>(baseh + (size_t)nA*EMBD + c4) = pk;
      }
      if (hasB){
        float deg = (float)(reB - rsB);
        uint2 hn = *(const uint2*)(hh + (size_t)nB*EMBD + c4);
        float ox = bB[0] + h2f((unsigned short)(hn.x & 0xffffu)) + sf4.x + deg*e24.x;
        float oy = bB[1] + h2f((unsigned short)(hn.x >> 16))     + sf4.y + deg*e24.y;
        float oz = bB[2] + h2f((unsigned short)(hn.y & 0xffffu)) + sf4.z + deg*e24.z;
        float ow = bB[3] + h2f((unsigned short)(hn.y >> 16))     + sf4.w + deg*e24.w;
        uint2 pk;
        pk.x = (unsigned)f2h(ox) | ((unsigned)f2h(oy) << 16);
        pk.y = (unsigned)f2h(oz) | ((unsigned)f2h(ow) << 16);
        *reinterpret_cast<uint2*>(baseh + (size_t)nB*EMBD + c4) = pk;
      }
    }
  } else {
    // ---------- S1 MFMA path (bf16 ew1 in regs, 2-node interleave), fp16 out ----------
    int lane = tid & 63;
    int lr = lane & 15, kb = lane >> 4;
    short8 bh[8];
    #pragma unroll
    for (int nf=0; nf<8; ++nf){
      int col = nf*16 + lr;
      ushort8 hh8;
      #pragma unroll
      for (int j=0;j<8;++j){
        int k = kb*8 + j;
        float v = 0.f;
        if (k < EDIM) v = ew1l[k*EMBD + col];
        else if (k == EDIM) v = eb1l[col];
        hh8[j] = f2b(v);
      }
      bh[nf] = *reinterpret_cast<short8*>(&hh8);
    }
    auto loadC = [&](int c0, int re)->short8{
      int cnt = re - c0;
      int idx = c0 + lr; if (idx > re-1) idx = re-1;
      short8 af = (short8)0;
      if (kb < 3){
        ushort8 t = *reinterpret_cast<const ushort8*>(eap24 + (size_t)idx*24 + kb*8);
        af = *reinterpret_cast<short8*>(&t);
      }
      if (lr >= cnt) af = (short8)0;
      return af;
    };
    const int GS = gridDim.x - GG;
    int wid = (blockIdx.x - GG)*4 + (tid>>6);
    const int NW = GS*4;
    for (int nA = wid; nA < NNODES; nA += 2*NW){
      int nB = nA + NW;
      bool hasB = (nB < NNODES);
      int rsA = rowptr[nA], reA = rowptr[nA+1];
      int rsB = 0, reB = 0;
      if (hasB){ rsB = rowptr[nB]; reB = rowptr[nB+1]; }
      float sA[8], sB[8];
      #pragma unroll
      for (int nf=0;nf<8;++nf){ sA[nf]=0.f; sB[nf]=0.f; }
      int cA = rsA, cB = rsB;
      while (cA < reA || cB < reB){
        bool dA = cA < reA, dB = cB < reB;
        short8 afA = (short8)0, afB = (short8)0;
        if (dA) afA = loadC(cA, reA);
        if (dB) afB = loadC(cB, reB);
        if (dA){
          #pragma unroll
          for (int nf=0;nf<8;++nf){
            f32x4 acc = (f32x4)0.f;
            acc = __builtin_amdgcn_mfma_f32_16x16x32_bf16(afA, bh[nf], acc, 0,0,0);
            #pragma unroll
            for (int j=0;j<4;++j){
              float v = acc[j];                  // leaky(v) = 0.55v + 0.45|v|
              sA[nf] = fmaf(0.55f, v, sA[nf]);
              sA[nf] = fmaf(0.45f, fabsf(v), sA[nf]);
            }
          }
        }
        if (dB){
          #pragma unroll
          for (int nf=0;nf<8;++nf){
            f32x4 acc = (f32x4)0.f;
            acc = __builtin_amdgcn_mfma_f32_16x16x32_bf16(afB, bh[nf], acc, 0,0,0);
            #pragma unroll
            for (int j=0;j<4;++j){
              float v = acc[j];
              sB[nf] = fmaf(0.55f, v, sB[nf]);
              sB[nf] = fmaf(0.45f, fabsf(v), sB[nf]);
            }
          }
        }
        cA += 16; cB += 16;
      }
      {
        #pragma unroll
        for (int nf=0;nf<8;++nf){
          float v = sA[nf];
          v += __shfl_xor(v, 16);
          v += __shfl_xor(v, 32);
          sA[nf] = v;
        }
        float va = sA[0], vb = sA[1];
        if (kb == 1){ va = sA[2]; vb = sA[3]; }
        if (kb == 2){ va = sA[4]; vb = sA[5]; }
        if (kb == 3){ va = sA[6]; vb = sA[7]; }
        s1h[(size_t)nA*EMBD + kb*32 + lr]      = f2h(va);
        s1h[(size_t)nA*EMBD + kb*32 + 16 + lr] = f2h(vb);
      }
      if (hasB){
        #pragma unroll
        for (int nf=0;nf<8;++nf){
          float v = sB[nf];
          v += __shfl_xor(v, 16);
          v += __shfl_xor(v, 32);
          sB[nf] = v;
        }
        float va = sB[0], vb = sB[1];
        if (kb == 1){ va = sB[2]; vb = sB[3]; }
        if (kb == 2){ va = sB[4]; vb = sB[5]; }
        if (kb == 3){ va = sB[6]; vb = sB[7]; }
        s1h[(size_t)nB*EMBD + kb*32 + lr]      = f2h(va);
        s1h[(size_t)nB*EMBD + kb*32 + 16 + lr] = f2h(vb);
      }
    }
  }
}

// ------------- tier-B combined edge dispatch (round-8/9 path, fp32 outputs) -------------
__global__ __launch_bounds__(256) void k_edge2(
    const unsigned short* __restrict__ hh, const int* __restrict__ rowptr,
    const int* __restrict__ srcp, const unsigned short* __restrict__ eap24,
    const float* __restrict__ ew1l, const float* __restrict__ eb1l,
    const float* __restrict__ eb2l, const float* __restrict__ selfel,
    float* __restrict__ S1, float* __restrict__ base, int GG)
{
  int tid = threadIdx.x;
  if ((int)blockIdx.x < GG){
    int li = tid & 31;
    int c4 = li*4;
    float4 sf4 = *(const float4*)(selfel + c4);
    float4 e24 = *(const float4*)(eb2l + c4);
    int slot = blockIdx.x*8 + (tid>>5);
    const int NS = GG*8;
    for (int node = slot; node < NNODES; node += NS){
      int rs = rowptr[node], re = rowptr[node+1];
      f32x4 b = (f32x4)0.f;
      for (int c0 = rs; c0 < re; c0 += 8){
        int cnt = re - c0;
        #pragma unroll
        for (int p=0;p<8;++p){
          int e = c0 + p; if (e > re-1) e = re-1;
          float m = (p < cnt) ? 1.f : 0.f;
          int sp = srcp[e];
          uint2 hv = *(const uint2*)(hh + (size_t)sp*EMBD + c4);
          b[0] = fmaf(m, h2f((unsigned short)(hv.x & 0xffffu)), b[0]);
          b[1] = fmaf(m, h2f((unsigned short)(hv.x >> 16)),     b[1]);
          b[2] = fmaf(m, h2f((unsigned short)(hv.y & 0xffffu)), b[2]);
          b[3] = fmaf(m, h2f((unsigned short)(hv.y >> 16)),     b[3]);
        }
      }
      float deg = (float)(re - rs);
      uint2 hn = *(const uint2*)(hh + (size_t)node*EMBD + c4);
      float4 o;
      o.x = b[0] + h2f((unsigned short)(hn.x & 0xffffu)) + sf4.x + deg*e24.x;
      o.y = b[1] + h2f((unsigned short)(hn.x >> 16))     + sf4.y + deg*e24.y;
      o.z = b[2] + h2f((unsigned short)(hn.y & 0xffffu)) + sf4.z + deg*e24.z;
      o.w = b[3] + h2f((unsigned short)(hn.y >> 16))     + sf4.w + deg*e24.w;
      *(float4*)(base + (size_t)node*EMBD + c4) = o;
    }
  } else {
    int lane = tid & 63;
    int lr = lane & 15, kb = lane >> 4;
    short8 bh[8];
    #pragma unroll
    for (int nf=0; nf<8; ++nf){
      int col = nf*16 + lr;
      ushort8 hh8;
      #pragma unroll
      for (int j=0;j<8;++j){
        int k = kb*8 + j;
        float v = 0.f;
        if (k < EDIM) v = ew1l[k*EMBD + col];
        else if (k == EDIM) v = eb1l[col];
        hh8[j] = f2b(v);
      }
      bh[nf] = *reinterpret_cast<short8*>(&hh8);
    }
    auto loadC = [&](int c0, int re)->short8{
      int cnt = re - c0;
      int idx = c0 + lr; if (idx > re-1) idx = re-1;
      short8 af = (short8)0;
      if (kb < 3){
        ushort8 t = *reinterpret_cast<const ushort8*>(eap24 + (size_t)idx*24 + kb*8);
        af = *reinterpret_cast<short8*>(&t);
      }
      if (lr >= cnt) af = (short8)0;
      return af;
    };
    const int GS = gridDim.x - GG;
    int wid = (blockIdx.x - GG)*4 + (tid>>6);
    const int NW = GS*4;
    for (int nA = wid; nA < NNODES; nA += 2*NW){
      int nB = nA + NW;
      bool hasB = (nB < NNODES);
      int rsA = rowptr[nA], reA = rowptr[nA+1];
      int rsB = 0, reB = 0;
      if (hasB){ rsB = rowptr[nB]; reB = rowptr[nB+1]; }
      float sA[8], sB[8];
      #pragma unroll
      for (int nf=0;nf<8;++nf){ sA[nf]=0.f; sB[nf]=0.f; }
      int cA = rsA, cB = rsB;
      while (cA < reA || cB < reB){
        bool dA = cA < reA, dB = cB < reB;
        short8 afA = (short8)0, afB = (short8)0;
        if (dA) afA = loadC(cA, reA);
        if (dB) afB = loadC(cB, reB);
        if (dA){
          #pragma unroll
          for (int nf=0;nf<8;++nf){
            f32x4 acc = (f32x4)0.f;
            acc = __builtin_amdgcn_mfma_f32_16x16x32_bf16(afA, bh[nf], acc, 0,0,0);
            #pragma unroll
            for (int j=0;j<4;++j){
              float v = acc[j];
              sA[nf] = fmaf(0.55f, v, sA[nf]);
              sA[nf] = fmaf(0.45f, fabsf(v), sA[nf]);
            }
          }
        }
        if (dB){
          #pragma unroll
          for (int nf=0;nf<8;++nf){
            f32x4 acc = (f32x4)0.f;
            acc = __builtin_amdgcn_mfma_f32_16x16x32_bf16(afB, bh[nf], acc, 0,0,0);
            #pragma unroll
            for (int j=0;j<4;++j){
              float v = acc[j];
              sB[nf] = fmaf(0.55f, v, sB[nf]);
              sB[nf] = fmaf(0.45f, fabsf(v), sB[nf]);
            }
          }
        }
        cA += 16; cB += 16;
      }
      {
        #pragma unroll
        for (int nf=0;nf<8;++nf){
          float v = sA[nf];
          v += __shfl_xor(v, 16);
          v += __shfl_xor(v, 32);
          sA[nf] = v;
        }
        float va = sA[0], vb = sA[1];
        if (kb == 1){ va = sA[2]; vb = sA[3]; }
        if (kb == 2){ va = sA[4]; vb = sA[5]; }
        if (kb == 3){ va = sA[6]; vb = sA[7]; }
        S1[(size_t)nA*EMBD + kb*32 + lr]      = va;
        S1[(size_t)nA*EMBD + kb*32 + 16 + lr] = vb;
      }
      if (hasB){
        #pragma unroll
        for (int nf=0;nf<8;++nf){
          float v = sB[nf];
          v += __shfl_xor(v, 16);
          v += __shfl_xor(v, 32);
          sB[nf] = v;
        }
        float va = sB[0], vb = sB[1];
        if (kb == 1){ va = sB[2]; vb = sB[3]; }
        if (kb == 2){ va = sB[4]; vb = sB[5]; }
        if (kb == 3){ va = sB[6]; vb = sB[7]; }
        S1[(size_t)nB*EMBD + kb*32 + lr]      = va;
        S1[(size_t)nB*EMBD + kb*32 + 16 + lr] = vb;
      }
    }
  }
}

// ------------- OLD edge kernel (tier-C fallback) -------------
__global__ __launch_bounds__(256) void k_edge(
    const float* __restrict__ h, const int* __restrict__ rowptr,
    const int* __restrict__ perm, const int* __restrict__ srcp,
    const float* __restrict__ edge_attr, const float* __restrict__ eaperm,
    const float* __restrict__ ew1l, const float* __restrict__ eb1l,
    const float* __restrict__ eb2l, const float* __restrict__ selfel,
    float* __restrict__ S1, float* __restrict__ base)
{
  __shared__ float w1s[EDIM*EMBD];
  __shared__ float b1s[EMBD];
  int tid = threadIdx.x;
  for (int i = tid; i < EDIM*EMBD; i += 256) w1s[i] = ew1l[i];
  if (tid < EMBD) b1s[tid] = eb1l[tid];
  __syncthreads();
  int lane = tid & 63;
  int node = blockIdx.x*4 + (tid >> 6);
  if (node >= NNODES) return;
  int rs = rowptr[node], re = rowptr[node+1];
  int c0 = lane*2;
  float s1x=0.f, s1y=0.f, bx=0.f, by=0.f;
  for (int i = rs; i < re; ++i){
    int s = __builtin_amdgcn_readfirstlane(srcp[i]);
    const float* ea;
    if (eaperm){
      ea = eaperm + (size_t)__builtin_amdgcn_readfirstlane(i)*EDIM;
    } else {
      ea = edge_attr + (size_t)__builtin_amdgcn_readfirstlane(perm[i])*EDIM;
    }
    float2 hs = *(const float2*)(h + (size_t)s*EMBD + c0);
    bx += hs.x; by += hs.y;
    float d0 = b1s[c0], d1 = b1s[c0+1];
    #pragma unroll
    for (int k=0;k<EDIM;++k){
      float av = ea[k];
      d0 += av * w1s[k*EMBD + c0];
      d1 += av * w1s[k*EMBD + c0 + 1];
    }
    s1x += leakyf(d0); s1y += leakyf(d1);
  }
  float deg = (float)(re - rs);
  float2 hv = *(const float2*)(h + (size_t)node*EMBD + c0);
  *(float2*)(S1 + (size_t)node*EMBD + c0) = make_float2(s1x, s1y);
  float bvx = bx + hv.x + selfel[c0]   + deg*eb2l[c0];
  float bvy = by + hv.y + selfel[c0+1] + deg*eb2l[c0+1];
  *(float2*)(base + (size_t)node*EMBD + c0) = make_float2(bvx, bvy);
}

// ------------- MFMA GEMM: C = act(A[M,K] @ B + bias), split-bf16 precision -------------
// A sources: fp32 (Af/A1, CONCAT), bf16 (Ab), or fp16 (Afh; with CONCAT: Afh first half, Afh2 second).
template<int BN, int WGM, int WGN, bool ALO, bool BLO, int ACT, bool STATS, bool OBF16,
         bool CONCAT, bool KCHK, bool ABF16, bool AH16>
__global__ __launch_bounds__(512) void k_mgemm(
    const float* __restrict__ Af, const float* __restrict__ A1,
    const __hip_bfloat16* __restrict__ Ab,
    const unsigned short* __restrict__ Afh, const unsigned short* __restrict__ Afh2,
    int M, int Kreal, int Kpad, int lda,
    const __hip_bfloat16* __restrict__ Bp,
    const float* __restrict__ bias,
    float* __restrict__ Cf, __hip_bfloat16* __restrict__ Cb, int ldc,
    float* __restrict__ stats, unsigned short* __restrict__ Ch)
{
  static_assert(WGM*WGN == 8, "8 waves");
  constexpr int BM = 128;
  constexpr int MF = BM/(16*WGM);
  constexpr int NF = BN/(16*WGN);
  constexpr int LDS_ROW = 40;
  __shared__ __align__(16) unsigned short Ah[BM*LDS_ROW];
  __shared__ __align__(16) unsigned short Al[ALO ? BM*LDS_ROW : 8];
  __shared__ float ssum[STATS ? BN : 4];
  __shared__ float ssq [STATS ? BN : 4];

  int tid = threadIdx.x;
  int row0 = blockIdx.x*BM;
  int w = tid >> 6, lane = tid & 63;
  int wm = w / WGN, wn = w % WGN;
  int lr = lane & 15, kb = lane >> 4;
  int wrow = wm*MF*16, wcol = wn*NF*16;

  if (STATS && tid < BN){ ssum[tid] = 0.f; ssq[tid] = 0.f; }

  f32x4 acc[MF][NF];
  #pragma unroll
  for (int a=0;a<MF;++a)
    #pragma unroll
    for (int b=0;b<NF;++b) acc[a][b] = (f32x4)0.f;

  const size_t planeSz = (size_t)Kpad*BN;
  int sr = tid >> 2;
  int skq = (tid & 3)*8;
  int grow = row0 + sr;
  const int KS = Kpad >> 5;

  for (int ks = 0; ks < KS; ++ks){
    int k0 = ks << 5;
    int kg = k0 + skq;
    ushort8 hv, lv;
    if (ABF16){
      short8 raw = (short8)0;
      if (grow < M) raw = *reinterpret_cast<const short8*>((const unsigned short*)Ab + (size_t)grow*lda + kg);
      hv = *reinterpret_cast<ushort8*>(&raw);
    } else {
      float v[8];
      if (AH16){
        const unsigned short* s16;
        if (CONCAT) s16 = (kg < EMBD) ? (Afh + (size_t)grow*EMBD + kg)
                                      : (Afh2 + (size_t)grow*EMBD + (kg - EMBD));
        else        s16 = Afh + (size_t)grow*lda + kg;
        ushort8 raw = (ushort8)0;
        if (grow < M) raw = *reinterpret_cast<const ushort8*>(s16);
        #pragma unroll
        for (int i=0;i<8;++i) v[i] = h2f(raw[i]);
      } else if (KCHK){
        #pragma unroll
        for (int i=0;i<8;++i)
          v[i] = (grow < M && kg+i < Kreal) ? Af[(size_t)grow*lda + kg + i] : 0.f;
      } else {
        const float* s;
        if (CONCAT) s = (kg < EMBD) ? (Af + (size_t)grow*lda + kg) : (A1 + (size_t)grow*lda + (kg - EMBD));
        else        s = Af + (size_t)grow*lda + kg;
        float4 p0 = make_float4(0,0,0,0), p1 = make_float4(0,0,0,0);
        if (grow < M){ p0 = *(const float4*)s; p1 = *(const float4*)(s+4); }
        v[0]=p0.x; v[1]=p0.y; v[2]=p0.z; v[3]=p0.w;
        v[4]=p1.x; v[5]=p1.y; v[6]=p1.z; v[7]=p1.w;
      }
      #pragma unroll
      for (int i=0;i<8;++i){
        unsigned short h16 = f2b(v[i]);
        hv[i] = h16;
        if (ALO) lv[i] = f2b(v[i] - b2f(h16));
      }
    }
    __syncthreads();
    *reinterpret_cast<ushort8*>(&Ah[sr*LDS_ROW + skq]) = hv;
    if (ALO && !ABF16) *reinterpret_cast<ushort8*>(&Al[sr*LDS_ROW + skq]) = lv;
    __syncthreads();

    short8 ah[MF], al[MF];
    #pragma unroll
    for (int mf=0; mf<MF; ++mf){
      int r = (wrow + mf*16 + lr)*LDS_ROW + kb*8;
      ah[mf] = *reinterpret_cast<const short8*>(&Ah[r]);
      if (ALO) al[mf] = *reinterpret_cast<const short8*>(&Al[r]);
    }
    const unsigned short* bb = (const unsigned short*)Bp + (size_t)ks*BN*32;
    short8 bh[NF], blv[NF];
    #pragma unroll
    for (int nf=0; nf<NF; ++nf){
      size_t off = (size_t)(wcol + nf*16 + lr)*32 + kb*8;
      bh[nf] = *reinterpret_cast<const short8*>(bb + off);
      if (BLO) blv[nf] = *reinterpret_cast<const short8*>(bb + planeSz + off);
    }
    #pragma unroll
    for (int mf=0; mf<MF; ++mf){
      #pragma unroll
      for (int nf=0; nf<NF; ++nf){
        acc[mf][nf] = __builtin_amdgcn_mfma_f32_16x16x32_bf16(ah[mf], bh[nf], acc[mf][nf], 0, 0, 0);
        if (BLO)
          acc[mf][nf] = __builtin_amdgcn_mfma_f32_16x16x32_bf16(ah[mf], blv[nf], acc[mf][nf], 0, 0, 0);
        if (ALO)
          acc[mf][nf] = __builtin_amdgcn_mfma_f32_16x16x32_bf16(al[mf], bh[nf], acc[mf][nf], 0, 0, 0);
      }
    }
  }

  float bcol[NF];
  #pragma unroll
  for (int nf=0; nf<NF; ++nf) bcol[nf] = bias ? bias[wcol + nf*16 + lr] : 0.f;
  float s[NF], sq[NF];
  #pragma unroll
  for (int nf=0; nf<NF; ++nf){ s[nf]=0.f; sq[nf]=0.f; }

  #pragma unroll
  for (int mf=0; mf<MF; ++mf){
    #pragma unroll
    for (int j=0; j<4; ++j){
      int r = row0 + wrow + mf*16 + kb*4 + j;
      if (r < M){
        #pragma unroll
        for (int nf=0; nf<NF; ++nf){
          int c = wcol + nf*16 + lr;
          float v = acc[mf][nf][j] + bcol[nf];
          if (ACT == 1) v = leakyf(v);
          if (ACT == 2) v = fmaxf(v, 0.f);
          if (OBF16) Cb[(size_t)r*ldc + c] = __float2bfloat16(v);
          else if (Cf) Cf[(size_t)r*ldc + c] = v;
          if (Ch) Ch[(size_t)r*ldc + c] = f2h(v);
          if (STATS){ s[nf] += v; sq[nf] += v*v; }
        }
      }
    }
  }
  if (STATS){
    #pragma unroll
    for (int nf=0; nf<NF; ++nf){
      atomicAdd(&ssum[wcol + nf*16 + lr], s[nf]);
      atomicAdd(&ssq [wcol + nf*16 + lr], sq[nf]);
    }
    __syncthreads();
    if (tid < BN){
      atomicAdd(&stats[tid], ssum[tid]);
      atomicAdd(&stats[BN + tid], ssq[tid]);
    }
  }
}

// ------------- BatchNorm normalize (+optional relu; fp32 and/or fp16 outputs) -------------
__global__ __launch_bounds__(256) void k_bn(const float* __restrict__ hh, const float* __restrict__ stats,
                                            const float* __restrict__ gamma, const float* __restrict__ beta,
                                            float* __restrict__ out, unsigned short* __restrict__ outh,
                                            int dorelu){
  int idx = blockIdx.x*256 + threadIdx.x;
  if (idx >= NNODES*(EMBD/4)) return;
  int c0 = (idx & (EMBD/4 - 1)) * 4;
  float4 v = *(const float4*)(hh + (size_t)idx*4);
  float o[4] = {v.x, v.y, v.z, v.w};
  const float invN = 1.f / (float)NNODES;
  #pragma unroll
  for (int i=0;i<4;++i){
    int c = c0 + i;
    float mean = stats[c] * invN;
    float var  = stats[EMBD + c] * invN - mean*mean;
    float inv  = rsqrtf(fmaxf(var, 0.f) + BNEPS);
    float y = (o[i] - mean) * inv * gamma[c] + beta[c];
    if (dorelu) y = fmaxf(y, 0.f);
    o[i] = y;
  }
  if (out) *(float4*)(out + (size_t)idx*4) = make_float4(o[0],o[1],o[2],o[3]);
  if (outh){
    uint2 pk;
    pk.x = (unsigned)f2h(o[0]) | ((unsigned)f2h(o[1]) << 16);
    pk.y = (unsigned)f2h(o[2]) | ((unsigned)f2h(o[3]) << 16);
    *reinterpret_cast<uint2*>(outh + (size_t)idx*4) = pk;
  }
}

// ---------------- launcher ----------------
extern "C" void kernel_launch(void* const* d_in, const int* in_sizes, int n_in,
                              void* d_out, int out_size, void* d_ws, size_t ws_size,
                              hipStream_t stream)
{
  const float* x   = (const float*)d_in[0];
  const float* ea  = (const float*)d_in[1];
  const float* iw1 = (const float*)d_in[2];
  const float* ib1 = (const float*)d_in[3];
  const float* iw2 = (const float*)d_in[4];
  const float* ib2 = (const float*)d_in[5];
  const float* ew1 = (const float*)d_in[6];
  const float* eb1 = (const float*)d_in[7];
  const float* ew2 = (const float*)d_in[8];
  const float* eb2 = (const float*)d_in[9];
  const float* mw1 = (const float*)d_in[10];
  const float* mb1 = (const float*)d_in[11];
  const float* mw2 = (const float*)d_in[12];
  const float* mb2 = (const float*)d_in[13];
  const float* gamma = (const float*)d_in[14];
  const float* beta  = (const float*)d_in[15];
  const int* eidx = (const int*)d_in[16];
  const int* srcI = eidx;
  const int* dstI = eidx + NEDGES;

  char* p = (char*)d_ws;
  auto alloc = [&](size_t bytes)->char*{
    char* r = p; p += (bytes + 255) & ~(size_t)255; return r;
  };
  float* S1    = (float*)alloc((size_t)NNODES*EMBD*4);
  float* base  = (float*)alloc((size_t)NNODES*EMBD*4);
  __hip_bfloat16* tbuf = (__hip_bfloat16*)alloc((size_t)NNODES*2*EMBD*2);
  int* perm   = (int*)alloc((size_t)NEDGES*4);     // == einv in new path
  int* srcp   = (int*)alloc((size_t)NEDGES*4);
  int* rowptr = (int*)alloc((size_t)(NNODES+1)*4);
  int* cursor = (int*)alloc((size_t)NNODES*4);
  int* bsum   = (int*)alloc(4096);
  int* boff   = (int*)alloc(4096);
  float* selfe = (float*)alloc(NLAYER*EMBD*4);
  float* stats = (float*)alloc(2*EMBD*4);
  float* wc    = (float*)alloc((size_t)NLAYER*EMBD*2*EMBD*4);
  __hip_bfloat16* Bi1 = (__hip_bfloat16*)alloc((size_t)192*EMBD*2*2);
  __hip_bfloat16* Bi2 = (__hip_bfloat16*)alloc((size_t)EMBD*EMBD*2*2);
  __hip_bfloat16* B1  = (__hip_bfloat16*)alloc((size_t)NLAYER*256*256*2*2);
  __hip_bfloat16* B2  = (__hip_bfloat16*)alloc((size_t)NLAYER*256*EMBD*2*2);
  size_t used = (size_t)(p - (char*)d_ws);

  const size_t szEap  = (size_t)NEDGES*24*2;
  const size_t szHh   = (size_t)NNODES*EMBD*2;
  const size_t szH16  = (size_t)NNODES*EMBD*2;
  const size_t szHbuf = (size_t)NNODES*EMBD*4;

  bool tierN = (ws_size >= used + szEap + szHh + 2*szH16 + 1024);   // fp16 S1/base path
  bool tierB = !tierN && (ws_size >= used + szEap + szHh + 512);
  unsigned short* eap24 = nullptr;
  unsigned short* hh16 = nullptr;
  unsigned short* s1h = nullptr;
  unsigned short* baseh = nullptr;
  float* hbuf = nullptr;
  float* eaperm = nullptr;
  if (tierN){
    eap24 = (unsigned short*)alloc(szEap);
    hh16  = (unsigned short*)alloc(szHh);
    s1h   = (unsigned short*)alloc(szH16);
    baseh = (unsigned short*)alloc(szH16);
  } else if (tierB){
    eap24 = (unsigned short*)alloc(szEap);
    hh16  = (unsigned short*)alloc(szHh);
  } else {
    hbuf = (float*)alloc(szHbuf);
    used = (size_t)(p - (char*)d_ws);
    if (ws_size >= used + (size_t)NEDGES*EDIM*4 + 256)
      eaperm = (float*)alloc((size_t)NEDGES*EDIM*4);
  }
  bool use_new = tierN || tierB;

  // ---- CSR build ----
  hipMemsetAsync(cursor, 0, (size_t)NNODES*4, stream);
  k_hist<<<(NEDGES+255)/256, 256, 0, stream>>>(dstI, cursor);
  int nb = (NNODES+255)/256;
  k_scan1<<<nb, 256, 0, stream>>>(cursor, rowptr, bsum);
  k_scan2<<<1, 512, 0, stream>>>(bsum, boff, nb);
  k_scan3<<<(NNODES+255)/256, 256, 0, stream>>>(rowptr, boff);
  k_curcopy<<<(NNODES+255)/256, 256, 0, stream>>>(rowptr, cursor);
  if (use_new){
    k_fill_pos<<<(NEDGES+255)/256, 256, 0, stream>>>(dstI, cursor, perm);
    k_fill_ea<<<(NEDGES+255)/256, 256, 0, stream>>>(perm, srcI, ea, srcp, eap24);
  } else {
    k_fill<<<(NEDGES+255)/256, 256, 0, stream>>>(srcI, dstI, ea, cursor, perm, srcp, eaperm);
  }
  k_selfe<<<NLAYER, EMBD, 0, stream>>>(eb1, ew2, eb2, selfe);

  // ---- weight prep ----
  k_wc<<<(NLAYER*EMBD*2*EMBD)/256, 256, 0, stream>>>(ew2, mw1, wc);
  k_pack<<<(192*EMBD+255)/256, 256, 0, stream>>>(iw1, XDIM, iw1, XDIM, 192, EMBD, Bi1);
  k_pack<<<(EMBD*EMBD+255)/256, 256, 0, stream>>>(iw2, EMBD, iw2, EMBD, EMBD, EMBD, Bi2);
  for (int l=0; l<NLAYER; ++l){
    k_pack<<<(256*256+255)/256, 256, 0, stream>>>(
        wc + (size_t)l*EMBD*2*EMBD, EMBD, mw1 + (size_t)l*EMBD*2*EMBD, 256, 256, 256,
        B1 + (size_t)l*256*256*2);
    k_pack<<<(256*EMBD+255)/256, 256, 0, stream>>>(
        mw2 + (size_t)l*2*EMBD*EMBD, 256, mw2, 256, 256, EMBD,
        B2 + (size_t)l*256*EMBD*2);
  }

  const int gx = (NNODES + 127)/128;

  // ---- input MLP ----
  k_mgemm<128,4,2, true,true,1,false,false,false,true ,false,false><<<gx, 512, 0, stream>>>(
      x, nullptr, nullptr, nullptr, nullptr, NNODES, XDIM, 192, XDIM, Bi1, ib1,
      S1, nullptr, EMBD, nullptr, nullptr);
  k_mgemm<128,4,2, true,true,0,false,false,false,false,false,false><<<gx, 512, 0, stream>>>(
      S1, nullptr, nullptr, nullptr, nullptr, NNODES, EMBD, EMBD, EMBD, Bi2, ib2,
      use_new ? nullptr : hbuf, nullptr, EMBD, nullptr, use_new ? hh16 : nullptr);

  for (int l=0; l<NLAYER; ++l){
    hipMemsetAsync(stats, 0, 2*EMBD*4, stream);
    if (tierN){
      k_edge4<<<2048, 256, 0, stream>>>(
          hh16, rowptr, srcp, eap24,
          ew1 + (size_t)l*EDIM*EMBD, eb1 + l*EMBD, eb2 + l*EMBD, selfe + l*EMBD,
          s1h, baseh, 1408);
      // t = relu([s1h|baseh](fp16) @ [Wc;mw1] + mb1) -> bf16 [N,256]  (A split hi+lo)
      k_mgemm<256,2,4, true,true,2,false,true ,true ,false,false,true ><<<gx, 512, 0, stream>>>(
          nullptr, nullptr, nullptr, s1h, baseh, NNODES, 256, 256, EMBD,
          B1 + (size_t)l*256*256*2, mb1 + l*2*EMBD, nullptr, tbuf, 2*EMBD, nullptr, nullptr);
    } else if (tierB){
      k_edge2<<<2048, 256, 0, stream>>>(
          hh16, rowptr, srcp, eap24,
          ew1 + (size_t)l*EDIM*EMBD, eb1 + l*EMBD, eb2 + l*EMBD, selfe + l*EMBD,
          S1, base, 1408);
      k_mgemm<256,2,4, true,true,2,false,true ,true ,false,false,false><<<gx, 512, 0, stream>>>(
          S1, base, nullptr, nullptr, nullptr, NNODES, 256, 256, EMBD,
          B1 + (size_t)l*256*256*2, mb1 + l*2*EMBD, nullptr, tbuf, 2*EMBD, nullptr, nullptr);
    } else {
      k_edge<<<NNODES/4, 256, 0, stream>>>(
          hbuf, rowptr, perm, srcp, ea, eaperm,
          ew1 + (size_t)l*EDIM*EMBD, eb1 + l*EMBD, eb2 + l*EMBD, selfe + l*EMBD,
          S1, base);
      k_mgemm<256,2,4, true,true,2,false,true ,true ,false,false,false><<<gx, 512, 0, stream>>>(
          S1, base, nullptr, nullptr, nullptr, NNODES, 256, 256, EMBD,
          B1 + (size_t)l*256*256*2, mb1 + l*2*EMBD, nullptr, tbuf, 2*EMBD, nullptr, nullptr);
    }
    // hh (into S1) = t @ mw2 + mb2, fused BN stats  (bf16 A, bf16-hi B only)
    k_mgemm<128,4,2, false,false,0,true ,false,false,false,true ,false><<<gx, 512, 0, stream>>>(
        nullptr, nullptr, tbuf, nullptr, nullptr, NNODES, 256, 256, 2*EMBD,
        B2 + (size_t)l*256*EMBD*2, mb2 + l*EMBD, S1, nullptr, EMBD, stats, nullptr);
    // BN normalize: intermediate layers -> fp16 h only; last layer -> fp32 d_out
    float* outp; unsigned short* outh;
    if (l == NLAYER-1){ outp = (float*)d_out; outh = nullptr; }
    else if (use_new) { outp = nullptr;       outh = hh16;    }
    else              { outp = hbuf;          outh = nullptr; }
    k_bn<<<(NNODES*(EMBD/4)+255)/256, 256, 0, stream>>>(
        S1, stats, gamma + l*EMBD, beta + l*EMBD, outp, outh, (l < NLAYER-1) ? 1 : 0);
  }
}